// Round 15
// baseline (624.210 us; speedup 1.0000x reference)
//
#include <hip/hip_runtime.h>
#include <hip/hip_bf16.h>
#include <math.h>

// GraphMAE: 3x GCNConv(relu) encoder -> 3-layer MLP decoder -> masked MSE.
// bf16 activation storage, f32 compute, MFMA bf16 matmuls.
// Round 15: W-LDS staging removed (B-fragments read directly from global;
// W is 32KB, L1/L2-resident, shared by all blocks) -> no stage barrier, LDS
// = 17.4KB transpose tile only, higher occupancy. Prep consolidated:
// dinv->scan1, compact->scan3, transw->cvt extra blocks.
// Outputs: d_out[0] = loss, d_out[1..N*128] = z (f32).

#define DD 128

typedef unsigned short ushort_t;
typedef unsigned int uint_t;
typedef __attribute__((ext_vector_type(8))) short short8;
typedef __attribute__((ext_vector_type(4))) float f32x4;

__device__ __forceinline__ ushort_t f2bf(float f) {
  union { float f; uint_t u; } v; v.f = f;
  uint_t r = v.u + 0x7fff + ((v.u >> 16) & 1);
  return (ushort_t)(r >> 16);
}
__device__ __forceinline__ float u2f(uint_t u) {
  union { uint_t u; float f; } v; v.u = u;
  return v.f;
}

// ---------------- dtype detection (edge_index: i64 vs i32; mask: i32 vs u8) ---
__global__ void detect_kernel(const void* edge, const void* mask,
                              long long E, int N, int* flags) {
  __shared__ int bad_e, bad_m;
  if (threadIdx.x == 0) { bad_e = 0; bad_m = 0; }
  __syncthreads();
  const long long* e64 = (const long long*)edge;
  long long step = E / 1024; if (step < 1) step = 1;
  for (int i = threadIdx.x; i < 1024; i += blockDim.x) {
    long long idx = (long long)i * step;
    if (idx < E) {
      long long v = e64[idx];
      if (v < 0 || v >= N) atomicAdd(&bad_e, 1);
    }
  }
  const int* m32 = (const int*)mask;
  int nw = N / 4;
  for (int i = threadIdx.x; i < nw; i += blockDim.x) {
    int v = m32[i];
    if (v != 0 && v != 1) atomicAdd(&bad_m, 1);
  }
  __syncthreads();
  if (threadIdx.x == 0) {
    flags[0] = (bad_e == 0) ? 1 : 0;
    flags[1] = (bad_m == 0) ? 1 : 0;
  }
}

__device__ __forceinline__ int load_mask(const void* p, int i, int is32) {
  if (is32) return ((const int*)p)[i];
  return (int)((const unsigned char*)p)[i];
}

// ------- edge convert to int32 + degree count; blocks >=1024 do transw ------
struct WPtrs { const float* w[6]; };
__global__ void cvt_kernel(const void* edge, long long E, int* s32, int* d32,
                           int* deg, const int* flags, WPtrs wp, ushort_t* wt) {
  if (blockIdx.x >= 1024) {  // weight transpose+cast: W[k][n] f32 -> WT[n][k]
    int wi = blockIdx.x - 1024;
    const float* W = wp.w[wi];
    ushort_t* dst = wt + wi * 16384;
    for (int i = threadIdx.x; i < 16384; i += blockDim.x) {
      int k = i >> 7, n = i & 127;
      dst[n * 128 + k] = f2bf(W[i]);
    }
    return;
  }
  int is64 = flags[0];
  long long i = blockIdx.x * 256LL + threadIdx.x;
  long long stride = 1024LL * 256LL;
  for (; i < E; i += stride) {
    int s, d;
    if (is64) {
      s = (int)((const long long*)edge)[i];
      d = (int)((const long long*)edge)[E + i];
    } else {
      s = ((const int*)edge)[i];
      d = ((const int*)edge)[E + i];
    }
    s32[i] = s;
    d32[i] = d;
    atomicAdd(&deg[d], 1);
  }
}

// ---------------- exclusive scan (3-pass); scan1 also emits dinv ------------
__global__ void scan1_kernel(const int* cnt, int* row_excl, int* blocksums,
                             int N, float* dinv, int Npad) {
  __shared__ int s[1024];
  int t = threadIdx.x, g = blockIdx.x * 1024 + t;
  int v = (g < N) ? cnt[g] : 0;
  if (g < Npad) dinv[g] = (g < N) ? rsqrtf((float)v + 1.0f) : 0.f;
  s[t] = v;
  __syncthreads();
  for (int off = 1; off < 1024; off <<= 1) {
    int add = (t >= off) ? s[t - off] : 0;
    __syncthreads();
    s[t] += add;
    __syncthreads();
  }
  if (g < N) row_excl[g] = s[t] - v;
  if (t == 1023) blocksums[blockIdx.x] = s[1023];
}

__global__ void scan2_kernel(int* blocksums, int nb, int* row_ptr, int N) {
  if (threadIdx.x == 0 && blockIdx.x == 0) {
    int run = 0;
    for (int b = 0; b < nb; ++b) { int t = blocksums[b]; blocksums[b] = run; run += t; }
    row_ptr[N] = run;
  }
}

// scan3 also does mask compaction (order-free).
__global__ void scan3_kernel(int* row_ptr, const int* blocksums, int* cursor, int N,
                             const void* mask, const int* flags, int* mcnt, int* midx) {
  int g = blockIdx.x * 1024 + threadIdx.x;
  if (g < N) {
    int v = row_ptr[g] + blocksums[blockIdx.x];
    row_ptr[g] = v;
    cursor[g] = v;
    if (load_mask(mask, g, flags[1])) {
      int p = atomicAdd(mcnt, 1);
      midx[p] = g;
    }
  }
}

// ---------------- CSR fill body (dst-range partitioned, int32 streams) ------
__device__ __forceinline__ void fillp_body(const int* __restrict__ s32,
                                           const int* __restrict__ d32,
                                           long long E, int* cursor, int* csr_src,
                                           int N, int bid, int nb) {
  int part = bid & 7;
  int lo = (int)(((long long)N * part) >> 3);
  int hi = (int)(((long long)N * (part + 1)) >> 3);
  long long i = (long long)(bid >> 3) * 256 + threadIdx.x;
  long long stride = (long long)(nb >> 3) * 256;
  for (; i < E; i += stride) {
    int d = d32[i];
    if (d >= lo && d < hi) {
      int s = s32[i];
      int pos = atomicAdd(&cursor[d], 1);
      csr_src[pos] = s;
    }
  }
}

// ---------------- MFMA helper: 128-K matmul, B direct from global WT --------
__device__ __forceinline__ void mfma_128g(const short8 a[4], f32x4 acc[8],
                                          const ushort_t* __restrict__ WT, int l) {
#pragma unroll
  for (int ks = 0; ks < 4; ++ks) {
#pragma unroll
    for (int c = 0; c < 8; ++c) {
      int nn = c * 16 + (l & 15);
      short8 b = *(const short8*)(WT + nn * 128 + ks * 32 + ((l >> 4) << 3));
      acc[c] = __builtin_amdgcn_mfma_f32_16x16x32_bf16(a[ks], b, acc[c], 0, 0, 0);
    }
  }
}

// ---------------- MFMA matmul body (encoder): out = A@W, LDS-transposed store
// BM=64 (4 waves x 16 rows). LDS = 17408B output-transpose tile only.
__device__ __forceinline__ void mm_body(
    const ushort_t* __restrict__ A, const float* __restrict__ Af32,
    int nvalid, const ushort_t* __restrict__ WT,
    ushort_t* __restrict__ outb, int nrows,
    const float* __restrict__ scale, int bid, char* lds) {
  if ((long long)bid * 64 >= nrows) return;

  int tid = threadIdx.x, w = tid >> 6, l = tid & 63;
  long long R0 = (long long)bid * 64 + w * 16;
  f32x4 acc[8];
#pragma unroll
  for (int c = 0; c < 8; ++c) acc[c] = (f32x4){0.f, 0.f, 0.f, 0.f};

  int r_log = (int)R0 + (l & 15);
  short8 a[4];
  if (Af32) {
    if (r_log < nvalid) {
      const float* ar = Af32 + (long long)r_log * 128 + ((l >> 4) << 3);
      float4 f0[4], f1[4];
#pragma unroll
      for (int ks = 0; ks < 4; ++ks) {
        f0[ks] = *(const float4*)(ar + ks * 32);
        f1[ks] = *(const float4*)(ar + ks * 32 + 4);
      }
#pragma unroll
      for (int ks = 0; ks < 4; ++ks) {
        a[ks][0] = (short)f2bf(f0[ks].x); a[ks][1] = (short)f2bf(f0[ks].y);
        a[ks][2] = (short)f2bf(f0[ks].z); a[ks][3] = (short)f2bf(f0[ks].w);
        a[ks][4] = (short)f2bf(f1[ks].x); a[ks][5] = (short)f2bf(f1[ks].y);
        a[ks][6] = (short)f2bf(f1[ks].z); a[ks][7] = (short)f2bf(f1[ks].w);
      }
    } else {
#pragma unroll
      for (int ks = 0; ks < 4; ++ks)
#pragma unroll
        for (int j = 0; j < 8; ++j) a[ks][j] = 0;
    }
  } else {
    const ushort_t* arow = A + (long long)r_log * 128 + ((l >> 4) << 3);
#pragma unroll
    for (int ks = 0; ks < 4; ++ks)
      a[ks] = *(const short8*)(arow + ks * 32);
  }

  mfma_128g(a, acc, WT, l);

  long long gr0 = R0 + ((l >> 4) << 2);
  float sc[4];
#pragma unroll
  for (int r = 0; r < 4; ++r)
    sc[r] = (gr0 + r < nrows) ? (scale ? scale[gr0 + r] : 1.f) : 0.f;

  // transpose through LDS (stride 272B), then 4x16B per thread
  int rbase = w * 16 + ((l >> 4) << 2);
#pragma unroll
  for (int c = 0; c < 8; ++c) {
    int col = c * 16 + (l & 15);
#pragma unroll
    for (int r = 0; r < 4; ++r) {
      float v = acc[c][r] * sc[r];
      *(ushort_t*)(lds + (rbase + r) * 272 + col * 2) = f2bf(v);
    }
  }
  __syncthreads();
  int row = tid >> 2, ck = tid & 3;
  long long grow = (long long)bid * 64 + row;
  if (grow < nrows) {
    const char* src = lds + row * 272 + ck * 64;
    ushort_t* dstp = outb + grow * 128 + ck * 32;
    *(short8*)(dstp)      = *(const short8*)(src);
    *(short8*)(dstp + 8)  = *(const short8*)(src + 16);
    *(short8*)(dstp + 16) = *(const short8*)(src + 32);
    *(short8*)(dstp + 24) = *(const short8*)(src + 48);
  }
}

__launch_bounds__(256, 8)
__global__ void mm_kernel(const ushort_t* __restrict__ A, const float* __restrict__ Af32,
                          int nvalid, const ushort_t* __restrict__ WT,
                          ushort_t* __restrict__ outb, int nrows,
                          const float* __restrict__ scale) {
  __shared__ __align__(16) char lds[17408];
  mm_body(A, Af32, nvalid, WT, outb, nrows, scale, blockIdx.x, lds);
}

// Fused dispatch: blocks < mmb run mm1 (x@W1 -> hb), the rest run CSR fill.
__launch_bounds__(256, 8)
__global__ void mmfill_kernel(const float* __restrict__ Af32, int nvalid,
                              const ushort_t* __restrict__ WT,
                              ushort_t* __restrict__ outb, int nrows,
                              const float* __restrict__ scale,
                              const int* __restrict__ s32, const int* __restrict__ d32,
                              long long E, int* cursor, int* csr_src, int N,
                              int mmb, int fillb) {
  __shared__ __align__(16) char lds[17408];
  if ((int)blockIdx.x < mmb) {
    mm_body(nullptr, Af32, nvalid, WT, outb, nrows, scale, blockIdx.x, lds);
  } else {
    fillp_body(s32, d32, E, cursor, csr_src, N, (int)blockIdx.x - mmb, fillb);
  }
}

// ---------------- fused decoder: d1 -> LDS tile -> d2 -> tile -> d3 -> loss --
__launch_bounds__(256, 6)
__global__ void dec_kernel(const ushort_t* __restrict__ Z,
                           const ushort_t* __restrict__ wtD,  // D1,D2,D3 (3*16384)
                           const float* __restrict__ db1,
                           const float* __restrict__ db2,
                           const float* __restrict__ db3,
                           const float* __restrict__ x,
                           const int* __restrict__ midx,
                           const int* __restrict__ gM,
                           float* __restrict__ accum) {
  __shared__ __align__(16) ushort_t tile[64 * 136];  // stride 272B
  int limit = *gM;
  int bid = blockIdx.x;
  if ((long long)bid * 64 >= limit) return;

  int tid = threadIdx.x, w = tid >> 6, l = tid & 63;
  long long R0 = (long long)bid * 64 + w * 16;
  int r_log = (int)R0 + (l & 15);
  long long r_phys = (r_log < limit) ? (long long)midx[r_log] : 0;
  int rbase = w * 16 + ((l >> 4) << 2);
  int trow = w * 16 + (l & 15);
  long long gr0 = R0 + ((l >> 4) << 2);

  // ---- layer 1: A from global (gathered z rows), W = D1
  short8 a[4];
  {
    const ushort_t* arow = Z + r_phys * 128 + ((l >> 4) << 3);
#pragma unroll
    for (int ks = 0; ks < 4; ++ks) a[ks] = *(const short8*)(arow + ks * 32);
  }
  f32x4 acc[8];
#pragma unroll
  for (int c = 0; c < 8; ++c) acc[c] = (f32x4){0.f, 0.f, 0.f, 0.f};
  mfma_128g(a, acc, wtD, l);
#pragma unroll
  for (int c = 0; c < 8; ++c) {
    int col = c * 16 + (l & 15);
    float bia = db1[col];
#pragma unroll
    for (int r = 0; r < 4; ++r)
      tile[(rbase + r) * 136 + col] = f2bf(fmaxf(acc[c][r] + bia, 0.f));
  }
  __syncthreads();

  // ---- layer 2: A from tile, W = D2
#pragma unroll
  for (int ks = 0; ks < 4; ++ks)
    a[ks] = *(const short8*)(tile + trow * 136 + ks * 32 + ((l >> 4) << 3));
  __syncthreads();  // all tile reads done before overwrite
#pragma unroll
  for (int c = 0; c < 8; ++c) acc[c] = (f32x4){0.f, 0.f, 0.f, 0.f};
  mfma_128g(a, acc, wtD + 16384, l);
#pragma unroll
  for (int c = 0; c < 8; ++c) {
    int col = c * 16 + (l & 15);
    float bia = db2[col];
#pragma unroll
    for (int r = 0; r < 4; ++r)
      tile[(rbase + r) * 136 + col] = f2bf(fmaxf(acc[c][r] + bia, 0.f));
  }
  __syncthreads();

  // ---- layer 3: A from tile, W = D3; fused masked-MSE (no stores)
#pragma unroll
  for (int ks = 0; ks < 4; ++ks)
    a[ks] = *(const short8*)(tile + trow * 136 + ks * 32 + ((l >> 4) << 3));
#pragma unroll
  for (int c = 0; c < 8; ++c) acc[c] = (f32x4){0.f, 0.f, 0.f, 0.f};
  mfma_128g(a, acc, wtD + 32768, l);

  float local_sq = 0.f;
#pragma unroll
  for (int c = 0; c < 8; ++c) {
    int col = c * 16 + (l & 15);
    float bia = db3[col];
#pragma unroll
    for (int r = 0; r < 4; ++r) {
      if (gr0 + r < limit) {
        int orow = midx[gr0 + r];
        float d = (acc[c][r] + bia) - x[(size_t)orow * 128 + col];
        local_sq += d * d;
      }
    }
  }
  float s = local_sq;
  for (int off2 = 32; off2; off2 >>= 1) s += __shfl_down(s, off2);
  __syncthreads();  // tile reads complete before reuse as scratch
  float* red = (float*)tile;
  if (l == 0) red[w] = s;
  __syncthreads();
  if (tid == 0) atomicAdd(accum, red[0] + red[1] + red[2] + red[3]);
}

// ---------------- GCN aggregation (wave/node; ht rows dinv-premultiplied) ----
// out[v] = relu(dv*(sum_{edges} ht[s] + ht[v]) + b); 8 gathers in flight.
__global__ void agg_kernel(const ushort_t* __restrict__ ht, const float* __restrict__ dinv,
                           const int* __restrict__ rp, const int* __restrict__ csr,
                           const float* __restrict__ bias, ushort_t* __restrict__ outb,
                           float* __restrict__ zout, int N) {
  int v = blockIdx.x * 4 + (threadIdx.x >> 6);
  if (v >= N) return;
  int l = threadIdx.x & 63;
  int off = l * 2;
  int e0 = __builtin_amdgcn_readfirstlane(rp[v]);
  int e1 = __builtin_amdgcn_readfirstlane(rp[v + 1]);

  float ax[8], ay[8];
#pragma unroll
  for (int j = 0; j < 8; ++j) { ax[j] = 0.f; ay[j] = 0.f; }

  int deg = e1 - e0;
  int nfull = deg & ~7;
  int efull = e0 + nfull;
  for (int e = e0; e < efull; e += 8) {
#pragma unroll
    for (int j = 0; j < 8; ++j) {
      int s = __builtin_amdgcn_readfirstlane(csr[e + j]);
      uint_t hv = *(const uint_t*)(ht + (size_t)s * 128 + off);
      ax[j] += u2f(hv << 16);
      ay[j] += u2f(hv & 0xffff0000u);
    }
  }
  if (efull < e1) {
#pragma unroll
    for (int j = 0; j < 8; ++j) {
      int idx = efull + j;
      int cs = __builtin_amdgcn_readfirstlane(csr[idx]);  // csr has +16 slack
      int s = (idx < e1) ? cs : N;                        // row N is all-zero
      uint_t hv = *(const uint_t*)(ht + (size_t)s * 128 + off);
      ax[j] += u2f(hv << 16);
      ay[j] += u2f(hv & 0xffff0000u);
    }
  }

  float dv = dinv[v];
  uint_t sv = *(const uint_t*)(ht + (size_t)v * 128 + off);
  float axs = ((ax[0] + ax[1]) + (ax[2] + ax[3])) + ((ax[4] + ax[5]) + (ax[6] + ax[7]));
  float ays = ((ay[0] + ay[1]) + (ay[2] + ay[3])) + ((ay[4] + ay[5]) + (ay[6] + ay[7]));
  axs += u2f(sv << 16);
  ays += u2f(sv & 0xffff0000u);
  float vx = fmaxf(dv * axs + bias[off], 0.f);
  float vy = fmaxf(dv * ays + bias[off + 1], 0.f);
  uint_t packed = (uint_t)f2bf(vx) | ((uint_t)f2bf(vy) << 16);
  *(uint_t*)(outb + (size_t)v * 128 + off) = packed;
  if (zout) {
    *(float2*)(zout + (size_t)v * 128 + off) = make_float2(vx, vy);
  }
}

__global__ void finalize_kernel(const float* accum, const int* cnt, float* out) {
  float denom = fmaxf((float)*cnt, 1.0f) * 128.0f;
  out[0] = *accum / denom;
}

// ---------------- launch ----------------
extern "C" void kernel_launch(void* const* d_in, const int* in_sizes, int n_in,
                              void* d_out, int out_size, void* d_ws, size_t ws_size,
                              hipStream_t stream) {
  const float* x  = (const float*)d_in[0];
  const void* edge = d_in[1];
  const void* mask = d_in[2];
  const float* W1 = (const float*)d_in[3];
  const float* b1 = (const float*)d_in[4];
  const float* W2 = (const float*)d_in[5];
  const float* b2 = (const float*)d_in[6];
  const float* W3 = (const float*)d_in[7];
  const float* b3 = (const float*)d_in[8];
  const float* D1 = (const float*)d_in[9];
  const float* db1 = (const float*)d_in[10];
  const float* D2 = (const float*)d_in[11];
  const float* db2 = (const float*)d_in[12];
  const float* D3 = (const float*)d_in[13];
  const float* db3 = (const float*)d_in[14];

  int N = in_sizes[0] / DD;
  long long E = in_sizes[1] / 2;
  long long Npad = ((long long)N + 63) & ~63LL;

  char* ws = (char*)d_ws;
  size_t p = 0;
  auto alloc = [&](size_t bytes) {
    size_t o = p;
    p = (p + bytes + 255) & ~(size_t)255;
    return o;
  };
  int* flags   = (int*)(ws + alloc(8));
  float* accum = (float*)(ws + alloc(4));
  int* mcnt    = (int*)(ws + alloc(4));
  int* deg     = (int*)(ws + alloc(sizeof(int) * N));
  float* dinv  = (float*)(ws + alloc(sizeof(float) * Npad));
  int* row_ptr = (int*)(ws + alloc(sizeof(int) * (N + 1)));
  int* cursor  = (int*)(ws + alloc(sizeof(int) * N));
  int* bsums   = (int*)(ws + alloc(sizeof(int) * 1024));
  int* midx    = (int*)(ws + alloc(sizeof(int) * N));
  int* s32     = (int*)(ws + alloc(sizeof(int) * E));
  int* d32     = (int*)(ws + alloc(sizeof(int) * E));
  int* csr     = (int*)(ws + alloc(sizeof(int) * (E + 16)));
  ushort_t* wt = (ushort_t*)(ws + alloc(sizeof(ushort_t) * 6 * 128 * 128));
  ushort_t* hb = (ushort_t*)(ws + alloc(sizeof(ushort_t) * (size_t)Npad * DD));
  ushort_t* gb = (ushort_t*)(ws + alloc(sizeof(ushort_t) * (size_t)Npad * DD));

  hipMemsetAsync(deg, 0, sizeof(int) * N, stream);
  hipMemsetAsync(accum, 0, 4, stream);
  hipMemsetAsync(mcnt, 0, 4, stream);
  // zero pad rows (N..Npad): row N is the agg-tail zero gather target.
  size_t padoff = (size_t)N * DD, padbytes = (size_t)(Npad - N) * DD * sizeof(ushort_t);
  hipMemsetAsync(hb + padoff, 0, padbytes, stream);
  hipMemsetAsync(gb + padoff, 0, padbytes, stream);

  // graph prep (transw rides as cvt blocks 1024..1029)
  WPtrs wp;
  wp.w[0] = W1; wp.w[1] = W2; wp.w[2] = W3;
  wp.w[3] = D1; wp.w[4] = D2; wp.w[5] = D3;
  detect_kernel<<<1, 256, 0, stream>>>(edge, mask, E, N, flags);
  cvt_kernel<<<1030, 256, 0, stream>>>(edge, E, s32, d32, deg, flags, wp, wt);
  int nb = (N + 1023) / 1024;
  scan1_kernel<<<nb, 1024, 0, stream>>>(deg, row_ptr, bsums, N, dinv, (int)Npad);
  scan2_kernel<<<1, 1, 0, stream>>>(bsums, nb, row_ptr, N);
  scan3_kernel<<<nb, 1024, 0, stream>>>(row_ptr, bsums, cursor, N,
                                        mask, flags, mcnt, midx);

  float* zout = (float*)d_out + 1;
  int mmb = (int)(Npad / 64);
  int aggb = (N + 3) / 4;
  int fillb = 4096;

  // fused: mm1 (x@W1 -> hb, dinv-scaled) concurrent with CSR fill
  mmfill_kernel<<<mmb + fillb, 256, 0, stream>>>(x, N, wt + 0 * 16384, hb,
                                                 (int)Npad, dinv, s32, d32, E,
                                                 cursor, csr, N, mmb, fillb);

  // encoder (mm stores ht = dinv * (A@W) in bf16)
  agg_kernel<<<aggb, 256, 0, stream>>>(hb, dinv, row_ptr, csr, b1, gb, nullptr, N);
  mm_kernel<<<mmb, 256, 0, stream>>>(gb, nullptr, 0, wt + 1 * 16384, hb,
                                     (int)Npad, dinv);
  agg_kernel<<<aggb, 256, 0, stream>>>(hb, dinv, row_ptr, csr, b2, gb, nullptr, N);
  mm_kernel<<<mmb, 256, 0, stream>>>(gb, nullptr, 0, wt + 2 * 16384, hb,
                                     (int)Npad, dinv);
  agg_kernel<<<aggb, 256, 0, stream>>>(hb, dinv, row_ptr, csr, b3, gb, zout, N);

  // fused decoder over compact masked rows (no global stores; loss direct)
  dec_kernel<<<mmb, 256, 0, stream>>>(gb, wt + 3 * 16384, db1, db2, db3,
                                      x, midx, mcnt, accum);

  finalize_kernel<<<1, 1, 0, stream>>>(accum, mcnt, (float*)d_out);
}

// Round 16
// 526.604 us; speedup vs baseline: 1.1853x; 1.1853x over previous
//
#include <hip/hip_runtime.h>
#include <hip/hip_bf16.h>
#include <math.h>

// GraphMAE: 3x GCNConv(relu) encoder -> 3-layer MLP decoder -> masked MSE.
// bf16 activation storage, f32 compute, MFMA bf16 matmuls.
// Round 16: W-direct-from-global reverted (round-15 regression: W refetch +
// global-latency MFMA operands). Back to round-14 LDS-staged W matmuls.
// Kept round-15 prep consolidation (transw in cvt, dinv in scan1, compact
// in scan3). mm1 fused with CSR fill; decoder fully fused with loss.
// Outputs: d_out[0] = loss, d_out[1..N*128] = z (f32).

#define DD 128

typedef unsigned short ushort_t;
typedef unsigned int uint_t;
typedef __attribute__((ext_vector_type(8))) short short8;
typedef __attribute__((ext_vector_type(4))) float f32x4;

__device__ __forceinline__ ushort_t f2bf(float f) {
  union { float f; uint_t u; } v; v.f = f;
  uint_t r = v.u + 0x7fff + ((v.u >> 16) & 1);
  return (ushort_t)(r >> 16);
}
__device__ __forceinline__ float u2f(uint_t u) {
  union { uint_t u; float f; } v; v.u = u;
  return v.f;
}

// ---------------- dtype detection (edge_index: i64 vs i32; mask: i32 vs u8) ---
__global__ void detect_kernel(const void* edge, const void* mask,
                              long long E, int N, int* flags) {
  __shared__ int bad_e, bad_m;
  if (threadIdx.x == 0) { bad_e = 0; bad_m = 0; }
  __syncthreads();
  const long long* e64 = (const long long*)edge;
  long long step = E / 1024; if (step < 1) step = 1;
  for (int i = threadIdx.x; i < 1024; i += blockDim.x) {
    long long idx = (long long)i * step;
    if (idx < E) {
      long long v = e64[idx];
      if (v < 0 || v >= N) atomicAdd(&bad_e, 1);
    }
  }
  const int* m32 = (const int*)mask;
  int nw = N / 4;
  for (int i = threadIdx.x; i < nw; i += blockDim.x) {
    int v = m32[i];
    if (v != 0 && v != 1) atomicAdd(&bad_m, 1);
  }
  __syncthreads();
  if (threadIdx.x == 0) {
    flags[0] = (bad_e == 0) ? 1 : 0;
    flags[1] = (bad_m == 0) ? 1 : 0;
  }
}

__device__ __forceinline__ int load_mask(const void* p, int i, int is32) {
  if (is32) return ((const int*)p)[i];
  return (int)((const unsigned char*)p)[i];
}

// ------- edge convert to int32 + degree count; blocks >=1024 do transw ------
struct WPtrs { const float* w[6]; };
__global__ void cvt_kernel(const void* edge, long long E, int* s32, int* d32,
                           int* deg, const int* flags, WPtrs wp, ushort_t* wt) {
  if (blockIdx.x >= 1024) {  // weight transpose+cast: W[k][n] f32 -> WT[n][k]
    int wi = blockIdx.x - 1024;
    const float* W = wp.w[wi];
    ushort_t* dst = wt + wi * 16384;
    for (int i = threadIdx.x; i < 16384; i += blockDim.x) {
      int k = i >> 7, n = i & 127;
      dst[n * 128 + k] = f2bf(W[i]);
    }
    return;
  }
  int is64 = flags[0];
  long long i = blockIdx.x * 256LL + threadIdx.x;
  long long stride = 1024LL * 256LL;
  for (; i < E; i += stride) {
    int s, d;
    if (is64) {
      s = (int)((const long long*)edge)[i];
      d = (int)((const long long*)edge)[E + i];
    } else {
      s = ((const int*)edge)[i];
      d = ((const int*)edge)[E + i];
    }
    s32[i] = s;
    d32[i] = d;
    atomicAdd(&deg[d], 1);
  }
}

// ---------------- exclusive scan (3-pass); scan1 also emits dinv ------------
__global__ void scan1_kernel(const int* cnt, int* row_excl, int* blocksums,
                             int N, float* dinv, int Npad) {
  __shared__ int s[1024];
  int t = threadIdx.x, g = blockIdx.x * 1024 + t;
  int v = (g < N) ? cnt[g] : 0;
  if (g < Npad) dinv[g] = (g < N) ? rsqrtf((float)v + 1.0f) : 0.f;
  s[t] = v;
  __syncthreads();
  for (int off = 1; off < 1024; off <<= 1) {
    int add = (t >= off) ? s[t - off] : 0;
    __syncthreads();
    s[t] += add;
    __syncthreads();
  }
  if (g < N) row_excl[g] = s[t] - v;
  if (t == 1023) blocksums[blockIdx.x] = s[1023];
}

__global__ void scan2_kernel(int* blocksums, int nb, int* row_ptr, int N) {
  if (threadIdx.x == 0 && blockIdx.x == 0) {
    int run = 0;
    for (int b = 0; b < nb; ++b) { int t = blocksums[b]; blocksums[b] = run; run += t; }
    row_ptr[N] = run;
  }
}

// scan3 also does mask compaction (order-free).
__global__ void scan3_kernel(int* row_ptr, const int* blocksums, int* cursor, int N,
                             const void* mask, const int* flags, int* mcnt, int* midx) {
  int g = blockIdx.x * 1024 + threadIdx.x;
  if (g < N) {
    int v = row_ptr[g] + blocksums[blockIdx.x];
    row_ptr[g] = v;
    cursor[g] = v;
    if (load_mask(mask, g, flags[1])) {
      int p = atomicAdd(mcnt, 1);
      midx[p] = g;
    }
  }
}

// ---------------- CSR fill body (dst-range partitioned, int32 streams) ------
__device__ __forceinline__ void fillp_body(const int* __restrict__ s32,
                                           const int* __restrict__ d32,
                                           long long E, int* cursor, int* csr_src,
                                           int N, int bid, int nb) {
  int part = bid & 7;
  int lo = (int)(((long long)N * part) >> 3);
  int hi = (int)(((long long)N * (part + 1)) >> 3);
  long long i = (long long)(bid >> 3) * 256 + threadIdx.x;
  long long stride = (long long)(nb >> 3) * 256;
  for (; i < E; i += stride) {
    int d = d32[i];
    if (d >= lo && d < hi) {
      int s = s32[i];
      int pos = atomicAdd(&cursor[d], 1);
      csr_src[pos] = s;
    }
  }
}

// ---------------- shared helpers for MFMA layers ----------------
__device__ __forceinline__ void stage_w(const ushort_t* __restrict__ WT, char* ldsW) {
  int tid = threadIdx.x;
  for (int cid = tid; cid < 2048; cid += 256) {
    int n = cid >> 4, kc = cid & 15;
    int dst = n * 256 + ((kc * 16) ^ ((n & 7) << 4));
    *(float4*)(ldsW + dst) = *(const float4*)(WT + n * 128 + kc * 8);
  }
}

__device__ __forceinline__ void mfma_128(const short8 a[4], f32x4 acc[8],
                                         const char* ldsW, int l) {
#pragma unroll
  for (int ks = 0; ks < 4; ++ks) {
#pragma unroll
    for (int c = 0; c < 8; ++c) {
      int nn = c * 16 + (l & 15);
      int kb = ks * 64 + ((l >> 4) << 4);
      short8 b = *(const short8*)(ldsW + nn * 256 + (kb ^ ((nn & 7) << 4)));
      acc[c] = __builtin_amdgcn_mfma_f32_16x16x32_bf16(a[ks], b, acc[c], 0, 0, 0);
    }
  }
}

// ---------------- MFMA matmul body (encoder): out = A@W, LDS-transposed store
__device__ __forceinline__ void mm_body(
    const ushort_t* __restrict__ A, const float* __restrict__ Af32,
    int nvalid, const ushort_t* __restrict__ WT,
    ushort_t* __restrict__ outb, int nrows,
    const float* __restrict__ scale, int bid, char* lds) {
  if ((long long)bid * 64 >= nrows) return;

  stage_w(WT, lds);
  __syncthreads();

  int tid = threadIdx.x, w = tid >> 6, l = tid & 63;
  long long R0 = (long long)bid * 64 + w * 16;
  f32x4 acc[8];
#pragma unroll
  for (int c = 0; c < 8; ++c) acc[c] = (f32x4){0.f, 0.f, 0.f, 0.f};

  int r_log = (int)R0 + (l & 15);
  short8 a[4];
  if (Af32) {
    if (r_log < nvalid) {
      const float* ar = Af32 + (long long)r_log * 128 + ((l >> 4) << 3);
      float4 f0[4], f1[4];
#pragma unroll
      for (int ks = 0; ks < 4; ++ks) {
        f0[ks] = *(const float4*)(ar + ks * 32);
        f1[ks] = *(const float4*)(ar + ks * 32 + 4);
      }
#pragma unroll
      for (int ks = 0; ks < 4; ++ks) {
        a[ks][0] = (short)f2bf(f0[ks].x); a[ks][1] = (short)f2bf(f0[ks].y);
        a[ks][2] = (short)f2bf(f0[ks].z); a[ks][3] = (short)f2bf(f0[ks].w);
        a[ks][4] = (short)f2bf(f1[ks].x); a[ks][5] = (short)f2bf(f1[ks].y);
        a[ks][6] = (short)f2bf(f1[ks].z); a[ks][7] = (short)f2bf(f1[ks].w);
      }
    } else {
#pragma unroll
      for (int ks = 0; ks < 4; ++ks)
#pragma unroll
        for (int j = 0; j < 8; ++j) a[ks][j] = 0;
    }
  } else {
    const ushort_t* arow = A + (long long)r_log * 128 + ((l >> 4) << 3);
#pragma unroll
    for (int ks = 0; ks < 4; ++ks)
      a[ks] = *(const short8*)(arow + ks * 32);
  }

  mfma_128(a, acc, lds, l);

  long long gr0 = R0 + ((l >> 4) << 2);
  float sc[4];
#pragma unroll
  for (int r = 0; r < 4; ++r)
    sc[r] = (gr0 + r < nrows) ? (scale ? scale[gr0 + r] : 1.f) : 0.f;

  // transpose through LDS (stride 272B), then 4x16B per thread
  __syncthreads();
  int rbase = w * 16 + ((l >> 4) << 2);
#pragma unroll
  for (int c = 0; c < 8; ++c) {
    int col = c * 16 + (l & 15);
#pragma unroll
    for (int r = 0; r < 4; ++r) {
      float v = acc[c][r] * sc[r];
      *(ushort_t*)(lds + (rbase + r) * 272 + col * 2) = f2bf(v);
    }
  }
  __syncthreads();
  int row = tid >> 2, ck = tid & 3;
  long long grow = (long long)bid * 64 + row;
  if (grow < nrows) {
    const char* src = lds + row * 272 + ck * 64;
    ushort_t* dstp = outb + grow * 128 + ck * 32;
    *(short8*)(dstp)      = *(const short8*)(src);
    *(short8*)(dstp + 8)  = *(const short8*)(src + 16);
    *(short8*)(dstp + 16) = *(const short8*)(src + 32);
    *(short8*)(dstp + 24) = *(const short8*)(src + 48);
  }
}

__launch_bounds__(256, 4)
__global__ void mm_kernel(const ushort_t* __restrict__ A, const float* __restrict__ Af32,
                          int nvalid, const ushort_t* __restrict__ WT,
                          ushort_t* __restrict__ outb, int nrows,
                          const float* __restrict__ scale) {
  __shared__ __align__(16) char lds[32768];
  mm_body(A, Af32, nvalid, WT, outb, nrows, scale, blockIdx.x, lds);
}

// Fused dispatch: blocks < mmb run mm1 (x@W1 -> hb), the rest run CSR fill.
__launch_bounds__(256, 4)
__global__ void mmfill_kernel(const float* __restrict__ Af32, int nvalid,
                              const ushort_t* __restrict__ WT,
                              ushort_t* __restrict__ outb, int nrows,
                              const float* __restrict__ scale,
                              const int* __restrict__ s32, const int* __restrict__ d32,
                              long long E, int* cursor, int* csr_src, int N,
                              int mmb, int fillb) {
  __shared__ __align__(16) char lds[32768];
  if ((int)blockIdx.x < mmb) {
    mm_body(nullptr, Af32, nvalid, WT, outb, nrows, scale, blockIdx.x, lds);
  } else {
    fillp_body(s32, d32, E, cursor, csr_src, N, (int)blockIdx.x - mmb, fillb);
  }
}

// ---------------- fused decoder: d1 -> LDS tile -> d2 -> tile -> d3 -> loss --
// Per block: 64 compact rows. Intermediates never leave LDS (stride 272B tile,
// 2-way bank reads = free). Loss accumulated directly from d3 accumulators.
__launch_bounds__(256, 3)
__global__ void dec_kernel(const ushort_t* __restrict__ Z,
                           const ushort_t* __restrict__ wtD,  // D1,D2,D3 (3*16384)
                           const float* __restrict__ db1,
                           const float* __restrict__ db2,
                           const float* __restrict__ db3,
                           const float* __restrict__ x,
                           const int* __restrict__ midx,
                           const int* __restrict__ gM,
                           float* __restrict__ accum) {
  __shared__ __align__(16) char ldsW[32768];
  __shared__ __align__(16) ushort_t tile[64 * 136];  // stride 272B
  int limit = *gM;
  int bid = blockIdx.x;
  if ((long long)bid * 64 >= limit) return;

  int tid = threadIdx.x, w = tid >> 6, l = tid & 63;
  long long R0 = (long long)bid * 64 + w * 16;
  int r_log = (int)R0 + (l & 15);
  long long r_phys = (r_log < limit) ? (long long)midx[r_log] : 0;
  int rbase = w * 16 + ((l >> 4) << 2);
  int trow = w * 16 + (l & 15);
  long long gr0 = R0 + ((l >> 4) << 2);

  // ---- layer 1: A from global (gathered z rows), W = D1
  stage_w(wtD, ldsW);
  short8 a[4];
  {
    const ushort_t* arow = Z + r_phys * 128 + ((l >> 4) << 3);
#pragma unroll
    for (int ks = 0; ks < 4; ++ks) a[ks] = *(const short8*)(arow + ks * 32);
  }
  __syncthreads();
  f32x4 acc[8];
#pragma unroll
  for (int c = 0; c < 8; ++c) acc[c] = (f32x4){0.f, 0.f, 0.f, 0.f};
  mfma_128(a, acc, ldsW, l);
  // relu(acc + db1) -> tile
#pragma unroll
  for (int c = 0; c < 8; ++c) {
    int col = c * 16 + (l & 15);
    float bia = db1[col];
#pragma unroll
    for (int r = 0; r < 4; ++r)
      tile[(rbase + r) * 136 + col] = f2bf(fmaxf(acc[c][r] + bia, 0.f));
  }
  __syncthreads();

  // ---- layer 2: A from tile, W = D2
  stage_w(wtD + 16384, ldsW);
#pragma unroll
  for (int ks = 0; ks < 4; ++ks)
    a[ks] = *(const short8*)(tile + trow * 136 + ks * 32 + ((l >> 4) << 3));
  __syncthreads();
#pragma unroll
  for (int c = 0; c < 8; ++c) acc[c] = (f32x4){0.f, 0.f, 0.f, 0.f};
  mfma_128(a, acc, ldsW, l);
  __syncthreads();  // tile reads done everywhere before overwrite
#pragma unroll
  for (int c = 0; c < 8; ++c) {
    int col = c * 16 + (l & 15);
    float bia = db2[col];
#pragma unroll
    for (int r = 0; r < 4; ++r)
      tile[(rbase + r) * 136 + col] = f2bf(fmaxf(acc[c][r] + bia, 0.f));
  }
  __syncthreads();

  // ---- layer 3: A from tile, W = D3; fused masked-MSE (no stores)
  stage_w(wtD + 32768, ldsW);
#pragma unroll
  for (int ks = 0; ks < 4; ++ks)
    a[ks] = *(const short8*)(tile + trow * 136 + ks * 32 + ((l >> 4) << 3));
  __syncthreads();
#pragma unroll
  for (int c = 0; c < 8; ++c) acc[c] = (f32x4){0.f, 0.f, 0.f, 0.f};
  mfma_128(a, acc, ldsW, l);

  float local_sq = 0.f;
#pragma unroll
  for (int c = 0; c < 8; ++c) {
    int col = c * 16 + (l & 15);
    float bia = db3[col];
#pragma unroll
    for (int r = 0; r < 4; ++r) {
      if (gr0 + r < limit) {
        int orow = midx[gr0 + r];
        float d = (acc[c][r] + bia) - x[(size_t)orow * 128 + col];
        local_sq += d * d;
      }
    }
  }
  float s = local_sq;
  for (int off2 = 32; off2; off2 >>= 1) s += __shfl_down(s, off2);
  __syncthreads();  // all tile reads complete before reuse as scratch
  float* red = (float*)tile;
  if (l == 0) red[w] = s;
  __syncthreads();
  if (tid == 0) atomicAdd(accum, red[0] + red[1] + red[2] + red[3]);
}

// ---------------- GCN aggregation (wave/node; ht rows dinv-premultiplied) ----
// out[v] = relu(dv*(sum_{edges} ht[s] + ht[v]) + b); 8 gathers in flight.
__global__ void agg_kernel(const ushort_t* __restrict__ ht, const float* __restrict__ dinv,
                           const int* __restrict__ rp, const int* __restrict__ csr,
                           const float* __restrict__ bias, ushort_t* __restrict__ outb,
                           float* __restrict__ zout, int N) {
  int v = blockIdx.x * 4 + (threadIdx.x >> 6);
  if (v >= N) return;
  int l = threadIdx.x & 63;
  int off = l * 2;
  int e0 = __builtin_amdgcn_readfirstlane(rp[v]);
  int e1 = __builtin_amdgcn_readfirstlane(rp[v + 1]);

  float ax[8], ay[8];
#pragma unroll
  for (int j = 0; j < 8; ++j) { ax[j] = 0.f; ay[j] = 0.f; }

  int deg = e1 - e0;
  int nfull = deg & ~7;
  int efull = e0 + nfull;
  for (int e = e0; e < efull; e += 8) {
#pragma unroll
    for (int j = 0; j < 8; ++j) {
      int s = __builtin_amdgcn_readfirstlane(csr[e + j]);
      uint_t hv = *(const uint_t*)(ht + (size_t)s * 128 + off);
      ax[j] += u2f(hv << 16);
      ay[j] += u2f(hv & 0xffff0000u);
    }
  }
  if (efull < e1) {
#pragma unroll
    for (int j = 0; j < 8; ++j) {
      int idx = efull + j;
      int cs = __builtin_amdgcn_readfirstlane(csr[idx]);  // csr has +16 slack
      int s = (idx < e1) ? cs : N;                        // row N is all-zero
      uint_t hv = *(const uint_t*)(ht + (size_t)s * 128 + off);
      ax[j] += u2f(hv << 16);
      ay[j] += u2f(hv & 0xffff0000u);
    }
  }

  float dv = dinv[v];
  uint_t sv = *(const uint_t*)(ht + (size_t)v * 128 + off);
  float axs = ((ax[0] + ax[1]) + (ax[2] + ax[3])) + ((ax[4] + ax[5]) + (ax[6] + ax[7]));
  float ays = ((ay[0] + ay[1]) + (ay[2] + ay[3])) + ((ay[4] + ay[5]) + (ay[6] + ay[7]));
  axs += u2f(sv << 16);
  ays += u2f(sv & 0xffff0000u);
  float vx = fmaxf(dv * axs + bias[off], 0.f);
  float vy = fmaxf(dv * ays + bias[off + 1], 0.f);
  uint_t packed = (uint_t)f2bf(vx) | ((uint_t)f2bf(vy) << 16);
  *(uint_t*)(outb + (size_t)v * 128 + off) = packed;
  if (zout) {
    *(float2*)(zout + (size_t)v * 128 + off) = make_float2(vx, vy);
  }
}

__global__ void finalize_kernel(const float* accum, const int* cnt, float* out) {
  float denom = fmaxf((float)*cnt, 1.0f) * 128.0f;
  out[0] = *accum / denom;
}

// ---------------- launch ----------------
extern "C" void kernel_launch(void* const* d_in, const int* in_sizes, int n_in,
                              void* d_out, int out_size, void* d_ws, size_t ws_size,
                              hipStream_t stream) {
  const float* x  = (const float*)d_in[0];
  const void* edge = d_in[1];
  const void* mask = d_in[2];
  const float* W1 = (const float*)d_in[3];
  const float* b1 = (const float*)d_in[4];
  const float* W2 = (const float*)d_in[5];
  const float* b2 = (const float*)d_in[6];
  const float* W3 = (const float*)d_in[7];
  const float* b3 = (const float*)d_in[8];
  const float* D1 = (const float*)d_in[9];
  const float* db1 = (const float*)d_in[10];
  const float* D2 = (const float*)d_in[11];
  const float* db2 = (const float*)d_in[12];
  const float* D3 = (const float*)d_in[13];
  const float* db3 = (const float*)d_in[14];

  int N = in_sizes[0] / DD;
  long long E = in_sizes[1] / 2;
  long long Npad = ((long long)N + 63) & ~63LL;

  char* ws = (char*)d_ws;
  size_t p = 0;
  auto alloc = [&](size_t bytes) {
    size_t o = p;
    p = (p + bytes + 255) & ~(size_t)255;
    return o;
  };
  int* flags   = (int*)(ws + alloc(8));
  float* accum = (float*)(ws + alloc(4));
  int* mcnt    = (int*)(ws + alloc(4));
  int* deg     = (int*)(ws + alloc(sizeof(int) * N));
  float* dinv  = (float*)(ws + alloc(sizeof(float) * Npad));
  int* row_ptr = (int*)(ws + alloc(sizeof(int) * (N + 1)));
  int* cursor  = (int*)(ws + alloc(sizeof(int) * N));
  int* bsums   = (int*)(ws + alloc(sizeof(int) * 1024));
  int* midx    = (int*)(ws + alloc(sizeof(int) * N));
  int* s32     = (int*)(ws + alloc(sizeof(int) * E));
  int* d32     = (int*)(ws + alloc(sizeof(int) * E));
  int* csr     = (int*)(ws + alloc(sizeof(int) * (E + 16)));
  ushort_t* wt = (ushort_t*)(ws + alloc(sizeof(ushort_t) * 6 * 128 * 128));
  ushort_t* hb = (ushort_t*)(ws + alloc(sizeof(ushort_t) * (size_t)Npad * DD));
  ushort_t* gb = (ushort_t*)(ws + alloc(sizeof(ushort_t) * (size_t)Npad * DD));

  hipMemsetAsync(deg, 0, sizeof(int) * N, stream);
  hipMemsetAsync(accum, 0, 4, stream);
  hipMemsetAsync(mcnt, 0, 4, stream);
  // zero pad rows (N..Npad): row N is the agg-tail zero gather target.
  size_t padoff = (size_t)N * DD, padbytes = (size_t)(Npad - N) * DD * sizeof(ushort_t);
  hipMemsetAsync(hb + padoff, 0, padbytes, stream);
  hipMemsetAsync(gb + padoff, 0, padbytes, stream);

  // graph prep (transw rides as cvt blocks 1024..1029)
  WPtrs wp;
  wp.w[0] = W1; wp.w[1] = W2; wp.w[2] = W3;
  wp.w[3] = D1; wp.w[4] = D2; wp.w[5] = D3;
  detect_kernel<<<1, 256, 0, stream>>>(edge, mask, E, N, flags);
  cvt_kernel<<<1030, 256, 0, stream>>>(edge, E, s32, d32, deg, flags, wp, wt);
  int nb = (N + 1023) / 1024;
  scan1_kernel<<<nb, 1024, 0, stream>>>(deg, row_ptr, bsums, N, dinv, (int)Npad);
  scan2_kernel<<<1, 1, 0, stream>>>(bsums, nb, row_ptr, N);
  scan3_kernel<<<nb, 1024, 0, stream>>>(row_ptr, bsums, cursor, N,
                                        mask, flags, mcnt, midx);

  float* zout = (float*)d_out + 1;
  int mmb = (int)(Npad / 64);
  int aggb = (N + 3) / 4;
  int fillb = 4096;

  // fused: mm1 (x@W1 -> hb, dinv-scaled) concurrent with CSR fill
  mmfill_kernel<<<mmb + fillb, 256, 0, stream>>>(x, N, wt + 0 * 16384, hb,
                                                 (int)Npad, dinv, s32, d32, E,
                                                 cursor, csr, N, mmb, fillb);

  // encoder (mm stores ht = dinv * (A@W) in bf16)
  agg_kernel<<<aggb, 256, 0, stream>>>(hb, dinv, row_ptr, csr, b1, gb, nullptr, N);
  mm_kernel<<<mmb, 256, 0, stream>>>(gb, nullptr, 0, wt + 1 * 16384, hb,
                                     (int)Npad, dinv);
  agg_kernel<<<aggb, 256, 0, stream>>>(hb, dinv, row_ptr, csr, b2, gb, nullptr, N);
  mm_kernel<<<mmb, 256, 0, stream>>>(gb, nullptr, 0, wt + 2 * 16384, hb,
                                     (int)Npad, dinv);
  agg_kernel<<<aggb, 256, 0, stream>>>(hb, dinv, row_ptr, csr, b3, gb, zout, N);

  // fused decoder over compact masked rows (no global stores; loss direct)
  dec_kernel<<<mmb, 256, 0, stream>>>(gb, wt + 3 * 16384, db1, db2, db3,
                                      x, midx, mcnt, accum);

  finalize_kernel<<<1, 1, 0, stream>>>(accum, mcnt, (float*)d_out);
}

// Round 17
// 452.128 us; speedup vs baseline: 1.3806x; 1.1647x over previous
//
#include <hip/hip_runtime.h>
#include <hip/hip_bf16.h>
#include <math.h>

// GraphMAE: 3x GCNConv(relu) encoder -> 3-layer MLP decoder -> masked MSE.
// Round 17: gather-source activations (hb) stored as FP8 e4m3 (128B rows,
// halves agg's random-gather traffic). mm epilogue encodes fp8 via
// v_cvt_pk_fp8_f32; agg decodes via v_cvt_pk_f32_fp8. Precision-critical
// buffers (gb = mm inputs + z, loss) stay bf16/f32.
// Outputs: d_out[0] = loss, d_out[1..N*128] = z (f32).

#define DD 128

typedef unsigned short ushort_t;
typedef unsigned int uint_t;
typedef unsigned char uchar_t;
typedef __attribute__((ext_vector_type(8))) short short8;
typedef __attribute__((ext_vector_type(4))) float f32x4;

__device__ __forceinline__ ushort_t f2bf(float f) {
  union { float f; uint_t u; } v; v.f = f;
  uint_t r = v.u + 0x7fff + ((v.u >> 16) & 1);
  return (ushort_t)(r >> 16);
}
__device__ __forceinline__ float u2f(uint_t u) {
  union { uint_t u; float f; } v; v.u = u;
  return v.f;
}
__device__ __forceinline__ uchar_t f2fp8(float f) {
  int pk = __builtin_amdgcn_cvt_pk_fp8_f32(f, f, 0, false);
  return (uchar_t)(pk & 0xff);
}

// ---------------- dtype detection (edge_index: i64 vs i32; mask: i32 vs u8) ---
__global__ void detect_kernel(const void* edge, const void* mask,
                              long long E, int N, int* flags) {
  __shared__ int bad_e, bad_m;
  if (threadIdx.x == 0) { bad_e = 0; bad_m = 0; }
  __syncthreads();
  const long long* e64 = (const long long*)edge;
  long long step = E / 1024; if (step < 1) step = 1;
  for (int i = threadIdx.x; i < 1024; i += blockDim.x) {
    long long idx = (long long)i * step;
    if (idx < E) {
      long long v = e64[idx];
      if (v < 0 || v >= N) atomicAdd(&bad_e, 1);
    }
  }
  const int* m32 = (const int*)mask;
  int nw = N / 4;
  for (int i = threadIdx.x; i < nw; i += blockDim.x) {
    int v = m32[i];
    if (v != 0 && v != 1) atomicAdd(&bad_m, 1);
  }
  __syncthreads();
  if (threadIdx.x == 0) {
    flags[0] = (bad_e == 0) ? 1 : 0;
    flags[1] = (bad_m == 0) ? 1 : 0;
  }
}

__device__ __forceinline__ int load_mask(const void* p, int i, int is32) {
  if (is32) return ((const int*)p)[i];
  return (int)((const unsigned char*)p)[i];
}

// ------- edge convert to int32 + degree count; blocks >=1024 do transw ------
struct WPtrs { const float* w[6]; };
__global__ void cvt_kernel(const void* edge, long long E, int* s32, int* d32,
                           int* deg, const int* flags, WPtrs wp, ushort_t* wt) {
  if (blockIdx.x >= 1024) {  // weight transpose+cast: W[k][n] f32 -> WT[n][k]
    int wi = blockIdx.x - 1024;
    const float* W = wp.w[wi];
    ushort_t* dst = wt + wi * 16384;
    for (int i = threadIdx.x; i < 16384; i += blockDim.x) {
      int k = i >> 7, n = i & 127;
      dst[n * 128 + k] = f2bf(W[i]);
    }
    return;
  }
  int is64 = flags[0];
  long long i = blockIdx.x * 256LL + threadIdx.x;
  long long stride = 1024LL * 256LL;
  for (; i < E; i += stride) {
    int s, d;
    if (is64) {
      s = (int)((const long long*)edge)[i];
      d = (int)((const long long*)edge)[E + i];
    } else {
      s = ((const int*)edge)[i];
      d = ((const int*)edge)[E + i];
    }
    s32[i] = s;
    d32[i] = d;
    atomicAdd(&deg[d], 1);
  }
}

// ---------------- exclusive scan (3-pass); scan1 also emits dinv ------------
__global__ void scan1_kernel(const int* cnt, int* row_excl, int* blocksums,
                             int N, float* dinv, int Npad) {
  __shared__ int s[1024];
  int t = threadIdx.x, g = blockIdx.x * 1024 + t;
  int v = (g < N) ? cnt[g] : 0;
  if (g < Npad) dinv[g] = (g < N) ? rsqrtf((float)v + 1.0f) : 0.f;
  s[t] = v;
  __syncthreads();
  for (int off = 1; off < 1024; off <<= 1) {
    int add = (t >= off) ? s[t - off] : 0;
    __syncthreads();
    s[t] += add;
    __syncthreads();
  }
  if (g < N) row_excl[g] = s[t] - v;
  if (t == 1023) blocksums[blockIdx.x] = s[1023];
}

__global__ void scan2_kernel(int* blocksums, int nb, int* row_ptr, int N) {
  if (threadIdx.x == 0 && blockIdx.x == 0) {
    int run = 0;
    for (int b = 0; b < nb; ++b) { int t = blocksums[b]; blocksums[b] = run; run += t; }
    row_ptr[N] = run;
  }
}

// scan3 also does mask compaction (order-free).
__global__ void scan3_kernel(int* row_ptr, const int* blocksums, int* cursor, int N,
                             const void* mask, const int* flags, int* mcnt, int* midx) {
  int g = blockIdx.x * 1024 + threadIdx.x;
  if (g < N) {
    int v = row_ptr[g] + blocksums[blockIdx.x];
    row_ptr[g] = v;
    cursor[g] = v;
    if (load_mask(mask, g, flags[1])) {
      int p = atomicAdd(mcnt, 1);
      midx[p] = g;
    }
  }
}

// ---------------- CSR fill body (dst-range partitioned, int32 streams) ------
__device__ __forceinline__ void fillp_body(const int* __restrict__ s32,
                                           const int* __restrict__ d32,
                                           long long E, int* cursor, int* csr_src,
                                           int N, int bid, int nb) {
  int part = bid & 7;
  int lo = (int)(((long long)N * part) >> 3);
  int hi = (int)(((long long)N * (part + 1)) >> 3);
  long long i = (long long)(bid >> 3) * 256 + threadIdx.x;
  long long stride = (long long)(nb >> 3) * 256;
  for (; i < E; i += stride) {
    int d = d32[i];
    if (d >= lo && d < hi) {
      int s = s32[i];
      int pos = atomicAdd(&cursor[d], 1);
      csr_src[pos] = s;
    }
  }
}

// ---------------- shared helpers for MFMA layers ----------------
__device__ __forceinline__ void stage_w(const ushort_t* __restrict__ WT, char* ldsW) {
  int tid = threadIdx.x;
  for (int cid = tid; cid < 2048; cid += 256) {
    int n = cid >> 4, kc = cid & 15;
    int dst = n * 256 + ((kc * 16) ^ ((n & 7) << 4));
    *(float4*)(ldsW + dst) = *(const float4*)(WT + n * 128 + kc * 8);
  }
}

__device__ __forceinline__ void mfma_128(const short8 a[4], f32x4 acc[8],
                                         const char* ldsW, int l) {
#pragma unroll
  for (int ks = 0; ks < 4; ++ks) {
#pragma unroll
    for (int c = 0; c < 8; ++c) {
      int nn = c * 16 + (l & 15);
      int kb = ks * 64 + ((l >> 4) << 4);
      short8 b = *(const short8*)(ldsW + nn * 256 + (kb ^ ((nn & 7) << 4)));
      acc[c] = __builtin_amdgcn_mfma_f32_16x16x32_bf16(a[ks], b, acc[c], 0, 0, 0);
    }
  }
}

// ---------------- MFMA matmul body (encoder): out = fp8(dinv * (A@W)) -------
// BM=64 (4 waves x 16 rows). A bf16 row-major OR f32 (in-register cast; rows
// >= nvalid read zero). WT bf16 [n][k] LDS-staged w/ XOR swizzle. Output
// encoded fp8 e4m3, transposed through LDS (stride 144B) -> 2x16B coalesced
// stores per thread.
__device__ __forceinline__ void mm_body(
    const ushort_t* __restrict__ A, const float* __restrict__ Af32,
    int nvalid, const ushort_t* __restrict__ WT,
    uchar_t* __restrict__ outb, int nrows,
    const float* __restrict__ scale, int bid, char* lds) {
  if ((long long)bid * 64 >= nrows) return;

  stage_w(WT, lds);
  __syncthreads();

  int tid = threadIdx.x, w = tid >> 6, l = tid & 63;
  long long R0 = (long long)bid * 64 + w * 16;
  f32x4 acc[8];
#pragma unroll
  for (int c = 0; c < 8; ++c) acc[c] = (f32x4){0.f, 0.f, 0.f, 0.f};

  int r_log = (int)R0 + (l & 15);
  short8 a[4];
  if (Af32) {
    if (r_log < nvalid) {
      const float* ar = Af32 + (long long)r_log * 128 + ((l >> 4) << 3);
      float4 f0[4], f1[4];
#pragma unroll
      for (int ks = 0; ks < 4; ++ks) {
        f0[ks] = *(const float4*)(ar + ks * 32);
        f1[ks] = *(const float4*)(ar + ks * 32 + 4);
      }
#pragma unroll
      for (int ks = 0; ks < 4; ++ks) {
        a[ks][0] = (short)f2bf(f0[ks].x); a[ks][1] = (short)f2bf(f0[ks].y);
        a[ks][2] = (short)f2bf(f0[ks].z); a[ks][3] = (short)f2bf(f0[ks].w);
        a[ks][4] = (short)f2bf(f1[ks].x); a[ks][5] = (short)f2bf(f1[ks].y);
        a[ks][6] = (short)f2bf(f1[ks].z); a[ks][7] = (short)f2bf(f1[ks].w);
      }
    } else {
#pragma unroll
      for (int ks = 0; ks < 4; ++ks)
#pragma unroll
        for (int j = 0; j < 8; ++j) a[ks][j] = 0;
    }
  } else {
    const ushort_t* arow = A + (long long)r_log * 128 + ((l >> 4) << 3);
#pragma unroll
    for (int ks = 0; ks < 4; ++ks)
      a[ks] = *(const short8*)(arow + ks * 32);
  }

  mfma_128(a, acc, lds, l);

  long long gr0 = R0 + ((l >> 4) << 2);
  float sc[4];
#pragma unroll
  for (int r = 0; r < 4; ++r)
    sc[r] = (gr0 + r < nrows) ? (scale ? scale[gr0 + r] : 1.f) : 0.f;

  // fp8 transpose through LDS (stride 144B), then 2x16B per thread
  __syncthreads();
  int rbase = w * 16 + ((l >> 4) << 2);
#pragma unroll
  for (int c = 0; c < 8; ++c) {
    int col = c * 16 + (l & 15);
#pragma unroll
    for (int r = 0; r < 4; ++r) {
      float v = acc[c][r] * sc[r];
      *(uchar_t*)(lds + (rbase + r) * 144 + col) = f2fp8(v);
    }
  }
  __syncthreads();
  int row = tid >> 2, ck = tid & 3;
  long long grow = (long long)bid * 64 + row;
  if (grow < nrows) {
    const char* src = lds + row * 144 + ck * 32;
    uchar_t* dstp = outb + grow * 128 + ck * 32;
    *(short8*)(dstp)      = *(const short8*)(src);
    *(short8*)(dstp + 16) = *(const short8*)(src + 16);
  }
}

__launch_bounds__(256, 4)
__global__ void mm_kernel(const ushort_t* __restrict__ A, const float* __restrict__ Af32,
                          int nvalid, const ushort_t* __restrict__ WT,
                          uchar_t* __restrict__ outb, int nrows,
                          const float* __restrict__ scale) {
  __shared__ __align__(16) char lds[32768];
  mm_body(A, Af32, nvalid, WT, outb, nrows, scale, blockIdx.x, lds);
}

// Fused dispatch: blocks < mmb run mm1 (x@W1 -> hb fp8), the rest run CSR fill.
__launch_bounds__(256, 4)
__global__ void mmfill_kernel(const float* __restrict__ Af32, int nvalid,
                              const ushort_t* __restrict__ WT,
                              uchar_t* __restrict__ outb, int nrows,
                              const float* __restrict__ scale,
                              const int* __restrict__ s32, const int* __restrict__ d32,
                              long long E, int* cursor, int* csr_src, int N,
                              int mmb, int fillb) {
  __shared__ __align__(16) char lds[32768];
  if ((int)blockIdx.x < mmb) {
    mm_body(nullptr, Af32, nvalid, WT, outb, nrows, scale, blockIdx.x, lds);
  } else {
    fillp_body(s32, d32, E, cursor, csr_src, N, (int)blockIdx.x - mmb, fillb);
  }
}

// ---------------- fused decoder: d1 -> LDS tile -> d2 -> tile -> d3 -> loss --
__launch_bounds__(256, 3)
__global__ void dec_kernel(const ushort_t* __restrict__ Z,
                           const ushort_t* __restrict__ wtD,  // D1,D2,D3 (3*16384)
                           const float* __restrict__ db1,
                           const float* __restrict__ db2,
                           const float* __restrict__ db3,
                           const float* __restrict__ x,
                           const int* __restrict__ midx,
                           const int* __restrict__ gM,
                           float* __restrict__ accum) {
  __shared__ __align__(16) char ldsW[32768];
  __shared__ __align__(16) ushort_t tile[64 * 136];  // stride 272B
  int limit = *gM;
  int bid = blockIdx.x;
  if ((long long)bid * 64 >= limit) return;

  int tid = threadIdx.x, w = tid >> 6, l = tid & 63;
  long long R0 = (long long)bid * 64 + w * 16;
  int r_log = (int)R0 + (l & 15);
  long long r_phys = (r_log < limit) ? (long long)midx[r_log] : 0;
  int rbase = w * 16 + ((l >> 4) << 2);
  int trow = w * 16 + (l & 15);
  long long gr0 = R0 + ((l >> 4) << 2);

  // ---- layer 1: A from global (gathered z rows), W = D1
  stage_w(wtD, ldsW);
  short8 a[4];
  {
    const ushort_t* arow = Z + r_phys * 128 + ((l >> 4) << 3);
#pragma unroll
    for (int ks = 0; ks < 4; ++ks) a[ks] = *(const short8*)(arow + ks * 32);
  }
  __syncthreads();
  f32x4 acc[8];
#pragma unroll
  for (int c = 0; c < 8; ++c) acc[c] = (f32x4){0.f, 0.f, 0.f, 0.f};
  mfma_128(a, acc, ldsW, l);
#pragma unroll
  for (int c = 0; c < 8; ++c) {
    int col = c * 16 + (l & 15);
    float bia = db1[col];
#pragma unroll
    for (int r = 0; r < 4; ++r)
      tile[(rbase + r) * 136 + col] = f2bf(fmaxf(acc[c][r] + bia, 0.f));
  }
  __syncthreads();

  // ---- layer 2: A from tile, W = D2
  stage_w(wtD + 16384, ldsW);
#pragma unroll
  for (int ks = 0; ks < 4; ++ks)
    a[ks] = *(const short8*)(tile + trow * 136 + ks * 32 + ((l >> 4) << 3));
  __syncthreads();
#pragma unroll
  for (int c = 0; c < 8; ++c) acc[c] = (f32x4){0.f, 0.f, 0.f, 0.f};
  mfma_128(a, acc, ldsW, l);
  __syncthreads();  // tile reads done everywhere before overwrite
#pragma unroll
  for (int c = 0; c < 8; ++c) {
    int col = c * 16 + (l & 15);
    float bia = db2[col];
#pragma unroll
    for (int r = 0; r < 4; ++r)
      tile[(rbase + r) * 136 + col] = f2bf(fmaxf(acc[c][r] + bia, 0.f));
  }
  __syncthreads();

  // ---- layer 3: A from tile, W = D3; fused masked-MSE (no stores)
  stage_w(wtD + 32768, ldsW);
#pragma unroll
  for (int ks = 0; ks < 4; ++ks)
    a[ks] = *(const short8*)(tile + trow * 136 + ks * 32 + ((l >> 4) << 3));
  __syncthreads();
#pragma unroll
  for (int c = 0; c < 8; ++c) acc[c] = (f32x4){0.f, 0.f, 0.f, 0.f};
  mfma_128(a, acc, ldsW, l);

  float local_sq = 0.f;
#pragma unroll
  for (int c = 0; c < 8; ++c) {
    int col = c * 16 + (l & 15);
    float bia = db3[col];
#pragma unroll
    for (int r = 0; r < 4; ++r) {
      if (gr0 + r < limit) {
        int orow = midx[gr0 + r];
        float d = (acc[c][r] + bia) - x[(size_t)orow * 128 + col];
        local_sq += d * d;
      }
    }
  }
  float s = local_sq;
  for (int off2 = 32; off2; off2 >>= 1) s += __shfl_down(s, off2);
  __syncthreads();  // all tile reads complete before reuse as scratch
  float* red = (float*)tile;
  if (l == 0) red[w] = s;
  __syncthreads();
  if (tid == 0) atomicAdd(accum, red[0] + red[1] + red[2] + red[3]);
}

// ---------------- GCN aggregation (wave/node; ht rows fp8, dinv-premult) -----
// out[v] = relu(dv*(sum_{edges} ht[s] + ht[v]) + b); 8 gathers in flight.
__global__ void agg_kernel(const uchar_t* __restrict__ ht, const float* __restrict__ dinv,
                           const int* __restrict__ rp, const int* __restrict__ csr,
                           const float* __restrict__ bias, ushort_t* __restrict__ outb,
                           float* __restrict__ zout, int N) {
  int v = blockIdx.x * 4 + (threadIdx.x >> 6);
  if (v >= N) return;
  int l = threadIdx.x & 63;
  int off = l * 2;  // byte offset = col index (fp8)
  int e0 = __builtin_amdgcn_readfirstlane(rp[v]);
  int e1 = __builtin_amdgcn_readfirstlane(rp[v + 1]);

  float ax[8], ay[8];
#pragma unroll
  for (int j = 0; j < 8; ++j) { ax[j] = 0.f; ay[j] = 0.f; }

  int deg = e1 - e0;
  int nfull = deg & ~7;
  int efull = e0 + nfull;
  for (int e = e0; e < efull; e += 8) {
#pragma unroll
    for (int j = 0; j < 8; ++j) {
      int s = __builtin_amdgcn_readfirstlane(csr[e + j]);
      int hv = *(const ushort_t*)(ht + (size_t)s * 128 + off);
      auto f = __builtin_amdgcn_cvt_pk_f32_fp8(hv, false);
      ax[j] += f[0];
      ay[j] += f[1];
    }
  }
  if (efull < e1) {
#pragma unroll
    for (int j = 0; j < 8; ++j) {
      int idx = efull + j;
      int cs = __builtin_amdgcn_readfirstlane(csr[idx]);  // csr has +16 slack
      int s = (idx < e1) ? cs : N;                        // row N is all-zero
      int hv = *(const ushort_t*)(ht + (size_t)s * 128 + off);
      auto f = __builtin_amdgcn_cvt_pk_f32_fp8(hv, false);
      ax[j] += f[0];
      ay[j] += f[1];
    }
  }

  float dv = dinv[v];
  int sv = *(const ushort_t*)(ht + (size_t)v * 128 + off);
  auto fs = __builtin_amdgcn_cvt_pk_f32_fp8(sv, false);
  float axs = ((ax[0] + ax[1]) + (ax[2] + ax[3])) + ((ax[4] + ax[5]) + (ax[6] + ax[7]));
  float ays = ((ay[0] + ay[1]) + (ay[2] + ay[3])) + ((ay[4] + ay[5]) + (ay[6] + ay[7]));
  axs += fs[0];
  ays += fs[1];
  float vx = fmaxf(dv * axs + bias[off], 0.f);
  float vy = fmaxf(dv * ays + bias[off + 1], 0.f);
  uint_t packed = (uint_t)f2bf(vx) | ((uint_t)f2bf(vy) << 16);
  *(uint_t*)(outb + (size_t)v * 128 + off) = packed;
  if (zout) {
    *(float2*)(zout + (size_t)v * 128 + off) = make_float2(vx, vy);
  }
}

__global__ void finalize_kernel(const float* accum, const int* cnt, float* out) {
  float denom = fmaxf((float)*cnt, 1.0f) * 128.0f;
  out[0] = *accum / denom;
}

// ---------------- launch ----------------
extern "C" void kernel_launch(void* const* d_in, const int* in_sizes, int n_in,
                              void* d_out, int out_size, void* d_ws, size_t ws_size,
                              hipStream_t stream) {
  const float* x  = (const float*)d_in[0];
  const void* edge = d_in[1];
  const void* mask = d_in[2];
  const float* W1 = (const float*)d_in[3];
  const float* b1 = (const float*)d_in[4];
  const float* W2 = (const float*)d_in[5];
  const float* b2 = (const float*)d_in[6];
  const float* W3 = (const float*)d_in[7];
  const float* b3 = (const float*)d_in[8];
  const float* D1 = (const float*)d_in[9];
  const float* db1 = (const float*)d_in[10];
  const float* D2 = (const float*)d_in[11];
  const float* db2 = (const float*)d_in[12];
  const float* D3 = (const float*)d_in[13];
  const float* db3 = (const float*)d_in[14];

  int N = in_sizes[0] / DD;
  long long E = in_sizes[1] / 2;
  long long Npad = ((long long)N + 63) & ~63LL;

  char* ws = (char*)d_ws;
  size_t p = 0;
  auto alloc = [&](size_t bytes) {
    size_t o = p;
    p = (p + bytes + 255) & ~(size_t)255;
    return o;
  };
  int* flags   = (int*)(ws + alloc(8));
  float* accum = (float*)(ws + alloc(4));
  int* mcnt    = (int*)(ws + alloc(4));
  int* deg     = (int*)(ws + alloc(sizeof(int) * N));
  float* dinv  = (float*)(ws + alloc(sizeof(float) * Npad));
  int* row_ptr = (int*)(ws + alloc(sizeof(int) * (N + 1)));
  int* cursor  = (int*)(ws + alloc(sizeof(int) * N));
  int* bsums   = (int*)(ws + alloc(sizeof(int) * 1024));
  int* midx    = (int*)(ws + alloc(sizeof(int) * N));
  int* s32     = (int*)(ws + alloc(sizeof(int) * E));
  int* d32     = (int*)(ws + alloc(sizeof(int) * E));
  int* csr     = (int*)(ws + alloc(sizeof(int) * (E + 16)));
  ushort_t* wt = (ushort_t*)(ws + alloc(sizeof(ushort_t) * 6 * 128 * 128));
  uchar_t* hb  = (uchar_t*)(ws + alloc((size_t)Npad * DD));           // fp8
  ushort_t* gb = (ushort_t*)(ws + alloc(sizeof(ushort_t) * (size_t)Npad * DD));

  hipMemsetAsync(deg, 0, sizeof(int) * N, stream);
  hipMemsetAsync(accum, 0, 4, stream);
  hipMemsetAsync(mcnt, 0, 4, stream);
  // zero pad rows (N..Npad): row N is the agg-tail zero gather target.
  hipMemsetAsync(hb + (size_t)N * DD, 0, (size_t)(Npad - N) * DD, stream);
  hipMemsetAsync(gb + (size_t)N * DD, 0,
                 (size_t)(Npad - N) * DD * sizeof(ushort_t), stream);

  // graph prep (transw rides as cvt blocks 1024..1029)
  WPtrs wp;
  wp.w[0] = W1; wp.w[1] = W2; wp.w[2] = W3;
  wp.w[3] = D1; wp.w[4] = D2; wp.w[5] = D3;
  detect_kernel<<<1, 256, 0, stream>>>(edge, mask, E, N, flags);
  cvt_kernel<<<1030, 256, 0, stream>>>(edge, E, s32, d32, deg, flags, wp, wt);
  int nb = (N + 1023) / 1024;
  scan1_kernel<<<nb, 1024, 0, stream>>>(deg, row_ptr, bsums, N, dinv, (int)Npad);
  scan2_kernel<<<1, 1, 0, stream>>>(bsums, nb, row_ptr, N);
  scan3_kernel<<<nb, 1024, 0, stream>>>(row_ptr, bsums, cursor, N,
                                        mask, flags, mcnt, midx);

  float* zout = (float*)d_out + 1;
  int mmb = (int)(Npad / 64);
  int aggb = (N + 3) / 4;
  int fillb = 4096;

  // fused: mm1 (x@W1 -> hb fp8, dinv-scaled) concurrent with CSR fill
  mmfill_kernel<<<mmb + fillb, 256, 0, stream>>>(x, N, wt + 0 * 16384, hb,
                                                 (int)Npad, dinv, s32, d32, E,
                                                 cursor, csr, N, mmb, fillb);

  // encoder (mm stores ht = fp8(dinv * (A@W)))
  agg_kernel<<<aggb, 256, 0, stream>>>(hb, dinv, row_ptr, csr, b1, gb, nullptr, N);
  mm_kernel<<<mmb, 256, 0, stream>>>(gb, nullptr, 0, wt + 1 * 16384, hb,
                                     (int)Npad, dinv);
  agg_kernel<<<aggb, 256, 0, stream>>>(hb, dinv, row_ptr, csr, b2, gb, nullptr, N);
  mm_kernel<<<mmb, 256, 0, stream>>>(gb, nullptr, 0, wt + 2 * 16384, hb,
                                     (int)Npad, dinv);
  agg_kernel<<<aggb, 256, 0, stream>>>(hb, dinv, row_ptr, csr, b3, gb, zout, N);

  // fused decoder over compact masked rows (no global stores; loss direct)
  dec_kernel<<<mmb, 256, 0, stream>>>(gb, wt + 3 * 16384, db1, db2, db3,
                                      x, midx, mcnt, accum);

  finalize_kernel<<<1, 1, 0, stream>>>(accum, mcnt, (float*)d_out);
}

// Round 18
// 432.149 us; speedup vs baseline: 1.4444x; 1.0462x over previous
//
#include <hip/hip_runtime.h>
#include <hip/hip_bf16.h>
#include <math.h>

// GraphMAE: 3x GCNConv(relu) encoder -> 3-layer MLP decoder -> masked MSE.
// Round 18: mm1 fused into the cvt dispatch (interleaved blocks; mm compute
// hides under cvt's atomic latency). Since dinv isn't available until scan1,
// mm1 stores UNscaled fp8 rows and scan1 is followed by hscale (folds dinv
// into hb rows; fused into fillp's grid as extra blocks). transw moved to
// detect dispatch. fp8 gather activations, fused decoder, LDS-transposed
// mm stores. Outputs: d_out[0] = loss, d_out[1..N*128] = z (f32).

#define DD 128

typedef unsigned short ushort_t;
typedef unsigned int uint_t;
typedef unsigned char uchar_t;
typedef __attribute__((ext_vector_type(8))) short short8;
typedef __attribute__((ext_vector_type(4))) float f32x4;

__device__ __forceinline__ ushort_t f2bf(float f) {
  union { float f; uint_t u; } v; v.f = f;
  uint_t r = v.u + 0x7fff + ((v.u >> 16) & 1);
  return (ushort_t)(r >> 16);
}
__device__ __forceinline__ float u2f(uint_t u) {
  union { uint_t u; float f; } v; v.u = u;
  return v.f;
}
__device__ __forceinline__ uchar_t f2fp8(float f) {
  int pk = __builtin_amdgcn_cvt_pk_fp8_f32(f, f, 0, false);
  return (uchar_t)(pk & 0xff);
}

// -------- detect (block 0) + weight transpose/cast (blocks 1..6) ------------
struct WPtrs { const float* w[6]; };
__global__ void detect_kernel(const void* edge, const void* mask,
                              long long E, int N, int* flags,
                              WPtrs wp, ushort_t* wt) {
  if (blockIdx.x >= 1) {  // transw: W[k][n] f32 -> WT[n][k] bf16
    int wi = blockIdx.x - 1;
    const float* W = wp.w[wi];
    ushort_t* dst = wt + wi * 16384;
    for (int i = threadIdx.x; i < 16384; i += blockDim.x) {
      int k = i >> 7, n = i & 127;
      dst[n * 128 + k] = f2bf(W[i]);
    }
    return;
  }
  __shared__ int bad_e, bad_m;
  if (threadIdx.x == 0) { bad_e = 0; bad_m = 0; }
  __syncthreads();
  const long long* e64 = (const long long*)edge;
  long long step = E / 1024; if (step < 1) step = 1;
  for (int i = threadIdx.x; i < 1024; i += blockDim.x) {
    long long idx = (long long)i * step;
    if (idx < E) {
      long long v = e64[idx];
      if (v < 0 || v >= N) atomicAdd(&bad_e, 1);
    }
  }
  const int* m32 = (const int*)mask;
  int nw = N / 4;
  for (int i = threadIdx.x; i < nw; i += blockDim.x) {
    int v = m32[i];
    if (v != 0 && v != 1) atomicAdd(&bad_m, 1);
  }
  __syncthreads();
  if (threadIdx.x == 0) {
    flags[0] = (bad_e == 0) ? 1 : 0;
    flags[1] = (bad_m == 0) ? 1 : 0;
  }
}

__device__ __forceinline__ int load_mask(const void* p, int i, int is32) {
  if (is32) return ((const int*)p)[i];
  return (int)((const unsigned char*)p)[i];
}

// ---------------- cvt body: edge -> int32 streams + degree atomics ----------
__device__ __forceinline__ void cvt_body(const void* edge, long long E,
                                         int* s32, int* d32, int* deg,
                                         const int* flags, int cid, int cvtb) {
  int is64 = flags[0];
  long long i = ((long long)cid * 256 + threadIdx.x) * 2;
  long long stride = (long long)cvtb * 512;
  for (; i < E; i += stride) {
    int s0, d0, s1 = 0, d1 = 0;
    bool has2 = (i + 1 < E);
    if (is64) {
      const long long* e64 = (const long long*)edge;
      s0 = (int)e64[i]; d0 = (int)e64[E + i];
      if (has2) { s1 = (int)e64[i + 1]; d1 = (int)e64[E + i + 1]; }
    } else {
      const int* e32 = (const int*)edge;
      s0 = e32[i]; d0 = e32[E + i];
      if (has2) { s1 = e32[i + 1]; d1 = e32[E + i + 1]; }
    }
    if (has2) {
      *(int2*)(s32 + i) = make_int2(s0, s1);
      *(int2*)(d32 + i) = make_int2(d0, d1);
      atomicAdd(&deg[d0], 1);
      atomicAdd(&deg[d1], 1);
    } else {
      s32[i] = s0; d32[i] = d0;
      atomicAdd(&deg[d0], 1);
    }
  }
}

// ---------------- exclusive scan (3-pass); scan1 also emits dinv ------------
__global__ void scan1_kernel(const int* cnt, int* row_excl, int* blocksums,
                             int N, float* dinv, int Npad) {
  __shared__ int s[1024];
  int t = threadIdx.x, g = blockIdx.x * 1024 + t;
  int v = (g < N) ? cnt[g] : 0;
  if (g < Npad) dinv[g] = (g < N) ? rsqrtf((float)v + 1.0f) : 0.f;
  s[t] = v;
  __syncthreads();
  for (int off = 1; off < 1024; off <<= 1) {
    int add = (t >= off) ? s[t - off] : 0;
    __syncthreads();
    s[t] += add;
    __syncthreads();
  }
  if (g < N) row_excl[g] = s[t] - v;
  if (t == 1023) blocksums[blockIdx.x] = s[1023];
}

__global__ void scan2_kernel(int* blocksums, int nb, int* row_ptr, int N) {
  if (threadIdx.x == 0 && blockIdx.x == 0) {
    int run = 0;
    for (int b = 0; b < nb; ++b) { int t = blocksums[b]; blocksums[b] = run; run += t; }
    row_ptr[N] = run;
  }
}

// scan3 also does mask compaction (order-free).
__global__ void scan3_kernel(int* row_ptr, const int* blocksums, int* cursor, int N,
                             const void* mask, const int* flags, int* mcnt, int* midx) {
  int g = blockIdx.x * 1024 + threadIdx.x;
  if (g < N) {
    int v = row_ptr[g] + blocksums[blockIdx.x];
    row_ptr[g] = v;
    cursor[g] = v;
    if (load_mask(mask, g, flags[1])) {
      int p = atomicAdd(mcnt, 1);
      midx[p] = g;
    }
  }
}

// ---------------- CSR fill + hscale (fold dinv into hb rows) ----------------
// Blocks [0, fillb): dst-range-partitioned CSR scatter.
// Blocks [fillb, fillb+hsb): hb[row] *= dinv[row] (fp8 decode/encode, 4 rows
// per block: 2 cols/lane). Independent work, concurrent.
__launch_bounds__(256, 4)
__global__ void fillhs_kernel(const int* __restrict__ s32, const int* __restrict__ d32,
                              long long E, int* cursor, int* csr_src, int N,
                              int fillb, uchar_t* __restrict__ hb,
                              const float* __restrict__ dinv) {
  int bid = blockIdx.x;
  if (bid < fillb) {
    int part = bid & 7;
    int lo = (int)(((long long)N * part) >> 3);
    int hi = (int)(((long long)N * (part + 1)) >> 3);
    long long i = (long long)(bid >> 3) * 256 + threadIdx.x;
    long long stride = (long long)(fillb >> 3) * 256;
    for (; i < E; i += stride) {
      int d = d32[i];
      if (d >= lo && d < hi) {
        int s = s32[i];
        int pos = atomicAdd(&cursor[d], 1);
        csr_src[pos] = s;
      }
    }
  } else {
    int row = (bid - fillb) * 4 + (threadIdx.x >> 6);
    if (row >= N) return;
    int l = threadIdx.x & 63;
    float dv = dinv[row];
    ushort_t* pp = (ushort_t*)(hb + (size_t)row * 128 + l * 2);
    int hv = *pp;
    auto f = __builtin_amdgcn_cvt_pk_f32_fp8(hv, false);
    int pk = __builtin_amdgcn_cvt_pk_fp8_f32(f[0] * dv, f[1] * dv, 0, false);
    *pp = (ushort_t)(pk & 0xffff);
  }
}

// ---------------- shared helpers for MFMA layers ----------------
__device__ __forceinline__ void stage_w(const ushort_t* __restrict__ WT, char* ldsW) {
  int tid = threadIdx.x;
  for (int cid = tid; cid < 2048; cid += 256) {
    int n = cid >> 4, kc = cid & 15;
    int dst = n * 256 + ((kc * 16) ^ ((n & 7) << 4));
    *(float4*)(ldsW + dst) = *(const float4*)(WT + n * 128 + kc * 8);
  }
}

__device__ __forceinline__ void mfma_128(const short8 a[4], f32x4 acc[8],
                                         const char* ldsW, int l) {
#pragma unroll
  for (int ks = 0; ks < 4; ++ks) {
#pragma unroll
    for (int c = 0; c < 8; ++c) {
      int nn = c * 16 + (l & 15);
      int kb = ks * 64 + ((l >> 4) << 4);
      short8 b = *(const short8*)(ldsW + nn * 256 + (kb ^ ((nn & 7) << 4)));
      acc[c] = __builtin_amdgcn_mfma_f32_16x16x32_bf16(a[ks], b, acc[c], 0, 0, 0);
    }
  }
}

// ---------------- MFMA matmul body (encoder): out = fp8(scale * (A@W)) ------
__device__ __forceinline__ void mm_body(
    const ushort_t* __restrict__ A, const float* __restrict__ Af32,
    int nvalid, const ushort_t* __restrict__ WT,
    uchar_t* __restrict__ outb, int nrows,
    const float* __restrict__ scale, int bid, char* lds) {
  if ((long long)bid * 64 >= nrows) return;

  stage_w(WT, lds);
  __syncthreads();

  int tid = threadIdx.x, w = tid >> 6, l = tid & 63;
  long long R0 = (long long)bid * 64 + w * 16;
  f32x4 acc[8];
#pragma unroll
  for (int c = 0; c < 8; ++c) acc[c] = (f32x4){0.f, 0.f, 0.f, 0.f};

  int r_log = (int)R0 + (l & 15);
  short8 a[4];
  if (Af32) {
    if (r_log < nvalid) {
      const float* ar = Af32 + (long long)r_log * 128 + ((l >> 4) << 3);
      float4 f0[4], f1[4];
#pragma unroll
      for (int ks = 0; ks < 4; ++ks) {
        f0[ks] = *(const float4*)(ar + ks * 32);
        f1[ks] = *(const float4*)(ar + ks * 32 + 4);
      }
#pragma unroll
      for (int ks = 0; ks < 4; ++ks) {
        a[ks][0] = (short)f2bf(f0[ks].x); a[ks][1] = (short)f2bf(f0[ks].y);
        a[ks][2] = (short)f2bf(f0[ks].z); a[ks][3] = (short)f2bf(f0[ks].w);
        a[ks][4] = (short)f2bf(f1[ks].x); a[ks][5] = (short)f2bf(f1[ks].y);
        a[ks][6] = (short)f2bf(f1[ks].z); a[ks][7] = (short)f2bf(f1[ks].w);
      }
    } else {
#pragma unroll
      for (int ks = 0; ks < 4; ++ks)
#pragma unroll
        for (int j = 0; j < 8; ++j) a[ks][j] = 0;
    }
  } else {
    const ushort_t* arow = A + (long long)r_log * 128 + ((l >> 4) << 3);
#pragma unroll
    for (int ks = 0; ks < 4; ++ks)
      a[ks] = *(const short8*)(arow + ks * 32);
  }

  mfma_128(a, acc, lds, l);

  long long gr0 = R0 + ((l >> 4) << 2);
  float sc[4];
#pragma unroll
  for (int r = 0; r < 4; ++r)
    sc[r] = (gr0 + r < nrows) ? (scale ? scale[gr0 + r] : 1.f) : 0.f;

  // fp8 transpose through LDS (stride 144B), then 2x16B per thread
  __syncthreads();
  int rbase = w * 16 + ((l >> 4) << 2);
#pragma unroll
  for (int c = 0; c < 8; ++c) {
    int col = c * 16 + (l & 15);
#pragma unroll
    for (int r = 0; r < 4; ++r) {
      float v = acc[c][r] * sc[r];
      *(uchar_t*)(lds + (rbase + r) * 144 + col) = f2fp8(v);
    }
  }
  __syncthreads();
  int row = tid >> 2, ck = tid & 3;
  long long grow = (long long)bid * 64 + row;
  if (grow < nrows) {
    const char* src = lds + row * 144 + ck * 32;
    uchar_t* dstp = outb + grow * 128 + ck * 32;
    *(short8*)(dstp)      = *(const short8*)(src);
    *(short8*)(dstp + 16) = *(const short8*)(src + 16);
  }
}

__launch_bounds__(256, 4)
__global__ void mm_kernel(const ushort_t* __restrict__ A, const float* __restrict__ Af32,
                          int nvalid, const ushort_t* __restrict__ WT,
                          uchar_t* __restrict__ outb, int nrows,
                          const float* __restrict__ scale) {
  __shared__ __align__(16) char lds[32768];
  mm_body(A, Af32, nvalid, WT, outb, nrows, scale, blockIdx.x, lds);
}

// Fused dispatch: interleaved blocks run cvt and mm1 (x@W1 -> hb, UNscaled;
// dinv folded in later by fillhs). Independent work, concurrent.
__launch_bounds__(256, 4)
__global__ void cvtmm_kernel(const void* edge, long long E, int* s32, int* d32,
                             int* deg, const int* flags,
                             const float* __restrict__ Af32, int nvalid,
                             const ushort_t* __restrict__ WT,
                             uchar_t* __restrict__ outb, int nrows,
                             int cvtb, int mmb) {
  __shared__ __align__(16) char lds[32768];
  int bid = blockIdx.x;
  int h = bid >> 1;
  if ((bid & 1) && h < mmb) {
    mm_body(nullptr, Af32, nvalid, WT, outb, nrows, nullptr, h, lds);
  } else {
    int cid = (h < mmb) ? h : (bid - mmb);
    cvt_body(edge, E, s32, d32, deg, flags, cid, cvtb);
  }
}

// ---------------- fused decoder: d1 -> LDS tile -> d2 -> tile -> d3 -> loss --
__launch_bounds__(256, 3)
__global__ void dec_kernel(const ushort_t* __restrict__ Z,
                           const ushort_t* __restrict__ wtD,
                           const float* __restrict__ db1,
                           const float* __restrict__ db2,
                           const float* __restrict__ db3,
                           const float* __restrict__ x,
                           const int* __restrict__ midx,
                           const int* __restrict__ gM,
                           float* __restrict__ accum) {
  __shared__ __align__(16) char ldsW[32768];
  __shared__ __align__(16) ushort_t tile[64 * 136];  // stride 272B
  int limit = *gM;
  int bid = blockIdx.x;
  if ((long long)bid * 64 >= limit) return;

  int tid = threadIdx.x, w = tid >> 6, l = tid & 63;
  long long R0 = (long long)bid * 64 + w * 16;
  int r_log = (int)R0 + (l & 15);
  long long r_phys = (r_log < limit) ? (long long)midx[r_log] : 0;
  int rbase = w * 16 + ((l >> 4) << 2);
  int trow = w * 16 + (l & 15);
  long long gr0 = R0 + ((l >> 4) << 2);

  stage_w(wtD, ldsW);
  short8 a[4];
  {
    const ushort_t* arow = Z + r_phys * 128 + ((l >> 4) << 3);
#pragma unroll
    for (int ks = 0; ks < 4; ++ks) a[ks] = *(const short8*)(arow + ks * 32);
  }
  __syncthreads();
  f32x4 acc[8];
#pragma unroll
  for (int c = 0; c < 8; ++c) acc[c] = (f32x4){0.f, 0.f, 0.f, 0.f};
  mfma_128(a, acc, ldsW, l);
#pragma unroll
  for (int c = 0; c < 8; ++c) {
    int col = c * 16 + (l & 15);
    float bia = db1[col];
#pragma unroll
    for (int r = 0; r < 4; ++r)
      tile[(rbase + r) * 136 + col] = f2bf(fmaxf(acc[c][r] + bia, 0.f));
  }
  __syncthreads();

  stage_w(wtD + 16384, ldsW);
#pragma unroll
  for (int ks = 0; ks < 4; ++ks)
    a[ks] = *(const short8*)(tile + trow * 136 + ks * 32 + ((l >> 4) << 3));
  __syncthreads();
#pragma unroll
  for (int c = 0; c < 8; ++c) acc[c] = (f32x4){0.f, 0.f, 0.f, 0.f};
  mfma_128(a, acc, ldsW, l);
  __syncthreads();
#pragma unroll
  for (int c = 0; c < 8; ++c) {
    int col = c * 16 + (l & 15);
    float bia = db2[col];
#pragma unroll
    for (int r = 0; r < 4; ++r)
      tile[(rbase + r) * 136 + col] = f2bf(fmaxf(acc[c][r] + bia, 0.f));
  }
  __syncthreads();

  stage_w(wtD + 32768, ldsW);
#pragma unroll
  for (int ks = 0; ks < 4; ++ks)
    a[ks] = *(const short8*)(tile + trow * 136 + ks * 32 + ((l >> 4) << 3));
  __syncthreads();
#pragma unroll
  for (int c = 0; c < 8; ++c) acc[c] = (f32x4){0.f, 0.f, 0.f, 0.f};
  mfma_128(a, acc, ldsW, l);

  float local_sq = 0.f;
#pragma unroll
  for (int c = 0; c < 8; ++c) {
    int col = c * 16 + (l & 15);
    float bia = db3[col];
#pragma unroll
    for (int r = 0; r < 4; ++r) {
      if (gr0 + r < limit) {
        int orow = midx[gr0 + r];
        float d = (acc[c][r] + bia) - x[(size_t)orow * 128 + col];
        local_sq += d * d;
      }
    }
  }
  float s = local_sq;
  for (int off2 = 32; off2; off2 >>= 1) s += __shfl_down(s, off2);
  __syncthreads();
  float* red = (float*)tile;
  if (l == 0) red[w] = s;
  __syncthreads();
  if (tid == 0) atomicAdd(accum, red[0] + red[1] + red[2] + red[3]);
}

// ---------------- GCN aggregation (wave/node; ht rows fp8, dinv-premult) -----
__global__ void agg_kernel(const uchar_t* __restrict__ ht, const float* __restrict__ dinv,
                           const int* __restrict__ rp, const int* __restrict__ csr,
                           const float* __restrict__ bias, ushort_t* __restrict__ outb,
                           float* __restrict__ zout, int N) {
  int v = blockIdx.x * 4 + (threadIdx.x >> 6);
  if (v >= N) return;
  int l = threadIdx.x & 63;
  int off = l * 2;
  int e0 = __builtin_amdgcn_readfirstlane(rp[v]);
  int e1 = __builtin_amdgcn_readfirstlane(rp[v + 1]);

  float ax[8], ay[8];
#pragma unroll
  for (int j = 0; j < 8; ++j) { ax[j] = 0.f; ay[j] = 0.f; }

  int deg = e1 - e0;
  int nfull = deg & ~7;
  int efull = e0 + nfull;
  for (int e = e0; e < efull; e += 8) {
#pragma unroll
    for (int j = 0; j < 8; ++j) {
      int s = __builtin_amdgcn_readfirstlane(csr[e + j]);
      int hv = *(const ushort_t*)(ht + (size_t)s * 128 + off);
      auto f = __builtin_amdgcn_cvt_pk_f32_fp8(hv, false);
      ax[j] += f[0];
      ay[j] += f[1];
    }
  }
  if (efull < e1) {
#pragma unroll
    for (int j = 0; j < 8; ++j) {
      int idx = efull + j;
      int cs = __builtin_amdgcn_readfirstlane(csr[idx]);
      int s = (idx < e1) ? cs : N;
      int hv = *(const ushort_t*)(ht + (size_t)s * 128 + off);
      auto f = __builtin_amdgcn_cvt_pk_f32_fp8(hv, false);
      ax[j] += f[0];
      ay[j] += f[1];
    }
  }

  float dv = dinv[v];
  int sv = *(const ushort_t*)(ht + (size_t)v * 128 + off);
  auto fs = __builtin_amdgcn_cvt_pk_f32_fp8(sv, false);
  float axs = ((ax[0] + ax[1]) + (ax[2] + ax[3])) + ((ax[4] + ax[5]) + (ax[6] + ax[7]));
  float ays = ((ay[0] + ay[1]) + (ay[2] + ay[3])) + ((ay[4] + ay[5]) + (ay[6] + ay[7]));
  axs += fs[0];
  ays += fs[1];
  float vx = fmaxf(dv * axs + bias[off], 0.f);
  float vy = fmaxf(dv * ays + bias[off + 1], 0.f);
  uint_t packed = (uint_t)f2bf(vx) | ((uint_t)f2bf(vy) << 16);
  *(uint_t*)(outb + (size_t)v * 128 + off) = packed;
  if (zout) {
    *(float2*)(zout + (size_t)v * 128 + off) = make_float2(vx, vy);
  }
}

__global__ void finalize_kernel(const float* accum, const int* cnt, float* out) {
  float denom = fmaxf((float)*cnt, 1.0f) * 128.0f;
  out[0] = *accum / denom;
}

// ---------------- launch ----------------
extern "C" void kernel_launch(void* const* d_in, const int* in_sizes, int n_in,
                              void* d_out, int out_size, void* d_ws, size_t ws_size,
                              hipStream_t stream) {
  const float* x  = (const float*)d_in[0];
  const void* edge = d_in[1];
  const void* mask = d_in[2];
  const float* W1 = (const float*)d_in[3];
  const float* b1 = (const float*)d_in[4];
  const float* W2 = (const float*)d_in[5];
  const float* b2 = (const float*)d_in[6];
  const float* W3 = (const float*)d_in[7];
  const float* b3 = (const float*)d_in[8];
  const float* D1 = (const float*)d_in[9];
  const float* db1 = (const float*)d_in[10];
  const float* D2 = (const float*)d_in[11];
  const float* db2 = (const float*)d_in[12];
  const float* D3 = (const float*)d_in[13];
  const float* db3 = (const float*)d_in[14];

  int N = in_sizes[0] / DD;
  long long E = in_sizes[1] / 2;
  long long Npad = ((long long)N + 63) & ~63LL;

  char* ws = (char*)d_ws;
  size_t p = 0;
  auto alloc = [&](size_t bytes) {
    size_t o = p;
    p = (p + bytes + 255) & ~(size_t)255;
    return o;
  };
  int* flags   = (int*)(ws + alloc(8));
  float* accum = (float*)(ws + alloc(4));
  int* mcnt    = (int*)(ws + alloc(4));
  int* deg     = (int*)(ws + alloc(sizeof(int) * N));
  float* dinv  = (float*)(ws + alloc(sizeof(float) * Npad));
  int* row_ptr = (int*)(ws + alloc(sizeof(int) * (N + 1)));
  int* cursor  = (int*)(ws + alloc(sizeof(int) * N));
  int* bsums   = (int*)(ws + alloc(sizeof(int) * 1024));
  int* midx    = (int*)(ws + alloc(sizeof(int) * N));
  int* s32     = (int*)(ws + alloc(sizeof(int) * (E + 2)));
  int* d32     = (int*)(ws + alloc(sizeof(int) * (E + 2)));
  int* csr     = (int*)(ws + alloc(sizeof(int) * (E + 16)));
  ushort_t* wt = (ushort_t*)(ws + alloc(sizeof(ushort_t) * 6 * 128 * 128));
  uchar_t* hb  = (uchar_t*)(ws + alloc((size_t)Npad * DD));           // fp8
  ushort_t* gb = (ushort_t*)(ws + alloc(sizeof(ushort_t) * (size_t)Npad * DD));

  hipMemsetAsync(deg, 0, sizeof(int) * N, stream);
  hipMemsetAsync(accum, 0, 4, stream);
  hipMemsetAsync(mcnt, 0, 4, stream);
  hipMemsetAsync(hb + (size_t)N * DD, 0, (size_t)(Npad - N) * DD, stream);
  hipMemsetAsync(gb + (size_t)N * DD, 0,
                 (size_t)(Npad - N) * DD * sizeof(ushort_t), stream);

  WPtrs wp;
  wp.w[0] = W1; wp.w[1] = W2; wp.w[2] = W3;
  wp.w[3] = D1; wp.w[4] = D2; wp.w[5] = D3;

  float* zout = (float*)d_out + 1;
  int mmb = (int)(Npad / 64);
  int aggb = (N + 3) / 4;
  int cvtb = 2048;
  int fillb = 4096;
  int hsb = (N + 3) / 4;

  // detect (block 0) + transw (blocks 1..6)
  detect_kernel<<<7, 256, 0, stream>>>(edge, mask, E, N, flags, wp, wt);

  // fused: cvt (edge->int32 + deg atomics) interleaved with mm1 (unscaled)
  cvtmm_kernel<<<cvtb + mmb, 256, 0, stream>>>(edge, E, s32, d32, deg, flags,
                                               x, N, wt + 0 * 16384, hb,
                                               (int)Npad, cvtb, mmb);

  int nb = (N + 1023) / 1024;
  scan1_kernel<<<nb, 1024, 0, stream>>>(deg, row_ptr, bsums, N, dinv, (int)Npad);
  scan2_kernel<<<1, 1, 0, stream>>>(bsums, nb, row_ptr, N);
  scan3_kernel<<<nb, 1024, 0, stream>>>(row_ptr, bsums, cursor, N,
                                        mask, flags, mcnt, midx);

  // CSR fill + hscale (hb *= dinv) concurrent
  fillhs_kernel<<<fillb + hsb, 256, 0, stream>>>(s32, d32, E, cursor, csr, N,
                                                 fillb, hb, dinv);

  // encoder
  agg_kernel<<<aggb, 256, 0, stream>>>(hb, dinv, row_ptr, csr, b1, gb, nullptr, N);
  mm_kernel<<<mmb, 256, 0, stream>>>(gb, nullptr, 0, wt + 1 * 16384, hb,
                                     (int)Npad, dinv);
  agg_kernel<<<aggb, 256, 0, stream>>>(hb, dinv, row_ptr, csr, b2, gb, nullptr, N);
  mm_kernel<<<mmb, 256, 0, stream>>>(gb, nullptr, 0, wt + 2 * 16384, hb,
                                     (int)Npad, dinv);
  agg_kernel<<<aggb, 256, 0, stream>>>(hb, dinv, row_ptr, csr, b3, gb, zout, N);

  // fused decoder
  dec_kernel<<<mmb, 256, 0, stream>>>(gb, wt + 3 * 16384, db1, db2, db3,
                                      x, midx, mcnt, accum);

  finalize_kernel<<<1, 1, 0, stream>>>(accum, mcnt, (float*)d_out);
}